// Round 1
// baseline (840.871 us; speedup 1.0000x reference)
//
#include <hip/hip_runtime.h>
#include <hip/hip_bf16.h>

// Problem constants
#define B_ 2
#define S_ 2048
#define H_ 8
#define HD_ 64
#define WIN_ 64
#define SUB_ 129      // 1 + 2*WIN
#define D_ 512        // H*HD
#define KS_ 2048
#define M_ 4096       // B*S
#define LN_EPS 1e-3f

// ---------------------------------------------------------------------------
// Tiled fp32 GEMM: C[M,N] = A[M,K] @ B[K,N] + bias[N]  (+ epilogue)
// EPI: 0 = bias only, 1 = bias+relu, 2 = bias + extra[row*eld+col]
// 64x64 tile, BK=16, 256 threads, 4x4 per-thread microtile.
// ---------------------------------------------------------------------------
template <int EPI>
__global__ __launch_bounds__(256) void gemm_kernel(
    const float* __restrict__ A, const float* __restrict__ Bm,
    const float* __restrict__ bias, const float* __restrict__ extra,
    float* __restrict__ C, int M, int N, int K, int lda, int ldb, int ldc,
    int eld) {
  __shared__ float As[16][68];  // stored transposed: As[k][m], pad to 68
  __shared__ float Bs[16][64];

  const int tid = threadIdx.x;
  const int tx = tid & 15;        // n-group
  const int ty = tid >> 4;        // m-group
  const int row0 = blockIdx.y << 6;
  const int col0 = blockIdx.x << 6;

  const int arow = tid >> 2;            // 0..63
  const int acol = (tid & 3) << 2;      // 0,4,8,12
  const int brow = tid >> 4;            // 0..15
  const int bcol = (tid & 15) << 2;     // 0..60

  const float* aptr = A + (size_t)(row0 + arow) * lda + acol;
  const float* bptr = Bm + (size_t)brow * ldb + col0 + bcol;

  float acc[4][4] = {};

  for (int k0 = 0; k0 < K; k0 += 16) {
    float4 av = *(const float4*)aptr;
    float4 bv = *(const float4*)bptr;
    aptr += 16;
    bptr += (size_t)16 * ldb;

    __syncthreads();  // previous iteration's reads done before overwrite
    As[acol + 0][arow] = av.x;
    As[acol + 1][arow] = av.y;
    As[acol + 2][arow] = av.z;
    As[acol + 3][arow] = av.w;
    *(float4*)&Bs[brow][bcol] = bv;
    __syncthreads();

#pragma unroll
    for (int kk = 0; kk < 16; ++kk) {
      float4 a = *(const float4*)&As[kk][ty << 2];
      float4 b = *(const float4*)&Bs[kk][tx << 2];
      acc[0][0] += a.x * b.x; acc[0][1] += a.x * b.y;
      acc[0][2] += a.x * b.z; acc[0][3] += a.x * b.w;
      acc[1][0] += a.y * b.x; acc[1][1] += a.y * b.y;
      acc[1][2] += a.y * b.z; acc[1][3] += a.y * b.w;
      acc[2][0] += a.z * b.x; acc[2][1] += a.z * b.y;
      acc[2][2] += a.z * b.z; acc[2][3] += a.z * b.w;
      acc[3][0] += a.w * b.x; acc[3][1] += a.w * b.y;
      acc[3][2] += a.w * b.z; acc[3][3] += a.w * b.w;
    }
  }

#pragma unroll
  for (int i = 0; i < 4; ++i) {
    const int row = row0 + (ty << 2) + i;
    const int colb = col0 + (tx << 2);
    float4 o;
    float* po = &o.x;
#pragma unroll
    for (int j = 0; j < 4; ++j) {
      float v = acc[i][j] + bias[colb + j];
      if (EPI == 1) v = fmaxf(v, 0.f);
      if (EPI == 2) v += extra[(size_t)row * eld + colb + j];
      po[j] = v;
    }
    *(float4*)&C[(size_t)row * ldc + colb] = o;
  }
}

// ---------------------------------------------------------------------------
// LayerNorm in-place on k (cols 0..511) and q (cols 512..1023) of kqv rows.
// grid = 2*M_ blocks (row = bs*2 + which), 128 threads, 4 elems/thread.
// ---------------------------------------------------------------------------
__global__ __launch_bounds__(128) void ln_kernel(float* __restrict__ kqv,
                                                 const float* __restrict__ gamma,
                                                 const float* __restrict__ beta) {
  const int row = blockIdx.x;
  const int bs = row >> 1;
  const int which = row & 1;  // 0 = k, 1 = q
  float* p = kqv + (size_t)bs * 1536 + (which ? 512 : 0);
  const int tid = threadIdx.x;
  const int c = tid << 2;

  float4 xv = *(float4*)&p[c];
  float s = xv.x + xv.y + xv.z + xv.w;
  float ss = xv.x * xv.x + xv.y * xv.y + xv.z * xv.z + xv.w * xv.w;

#pragma unroll
  for (int off = 32; off > 0; off >>= 1) {
    s += __shfl_down(s, off);
    ss += __shfl_down(ss, off);
  }
  __shared__ float red[4];
  if ((tid & 63) == 0) {
    red[(tid >> 6) * 2 + 0] = s;
    red[(tid >> 6) * 2 + 1] = ss;
  }
  __syncthreads();
  const float tot = red[0] + red[2];
  const float tots = red[1] + red[3];
  const float mean = tot * (1.f / 512.f);
  const float var = tots * (1.f / 512.f) - mean * mean;
  const float rstd = rsqrtf(var + LN_EPS);

  float4 g = *(const float4*)&gamma[c];
  float4 bb = *(const float4*)&beta[c];
  xv.x = (xv.x - mean) * rstd * g.x + bb.x;
  xv.y = (xv.y - mean) * rstd * g.y + bb.y;
  xv.z = (xv.z - mean) * rstd * g.z + bb.z;
  xv.w = (xv.w - mean) * rstd * g.w + bb.w;
  *(float4*)&p[c] = xv;
}

// ---------------------------------------------------------------------------
// Windowed attention. One block (128 threads) per (b, h, s).
// kqv row layout: [k(512) | q(512) | v(512)], heads of 64 within each.
// ctx[b*S+s][h*64+d] = softmax(q . k_window / 8) @ v_window
// ---------------------------------------------------------------------------
__global__ __launch_bounds__(128) void attn_kernel(const float* __restrict__ kqv,
                                                   float* __restrict__ ctx) {
  const int bid = blockIdx.x;       // ((b*H + h) * S + s)
  const int s = bid & (S_ - 1);
  const int h = (bid >> 11) & (H_ - 1);
  const int b = bid >> 14;

  int start = s - WIN_;
  if (start < 0) start = 0;
  if (start > S_ - SUB_) start = S_ - SUB_;

  __shared__ float ks[SUB_ * 65];  // stride 65 -> no bank conflicts
  __shared__ float qs[HD_];
  __shared__ float sc[SUB_];
  __shared__ float red[4];

  const int tid = threadIdx.x;
  const float* qptr = kqv + ((size_t)(b * S_ + s)) * 1536 + 512 + h * HD_;
  if (tid < 64) qs[tid] = qptr[tid];

  const float* kbase = kqv + ((size_t)(b * S_ + start)) * 1536 + h * HD_;
  for (int i = tid; i < SUB_ * HD_; i += 128) {
    const int w = i >> 6;
    const int d = i & 63;
    ks[w * 65 + d] = kbase[(size_t)w * 1536 + d];
  }
  __syncthreads();

  // scores
  for (int w = tid; w < SUB_; w += 128) {
    float dot = 0.f;
#pragma unroll
    for (int d = 0; d < 64; ++d) dot += qs[d] * ks[w * 65 + d];
    sc[w] = dot * 0.125f;
  }
  __syncthreads();

  // softmax (max, exp, sum)
  float lm = -1e30f;
  for (int w = tid; w < SUB_; w += 128) lm = fmaxf(lm, sc[w]);
#pragma unroll
  for (int off = 32; off > 0; off >>= 1) lm = fmaxf(lm, __shfl_down(lm, off));
  if ((tid & 63) == 0) red[tid >> 6] = lm;
  __syncthreads();
  const float gmax = fmaxf(red[0], red[1]);

  float lsum = 0.f;
  for (int w = tid; w < SUB_; w += 128) {
    const float e = __expf(sc[w] - gmax);
    sc[w] = e;
    lsum += e;
  }
#pragma unroll
  for (int off = 32; off > 0; off >>= 1) lsum += __shfl_down(lsum, off);
  if ((tid & 63) == 0) red[2 + (tid >> 6)] = lsum;
  __syncthreads();
  const float inv = 1.f / (red[2] + red[3]);

  // ctx = attn @ V   (threads 0..63 = d; V loads coalesced across lanes)
  if (tid < 64) {
    const float* vbase =
        kqv + ((size_t)(b * S_ + start)) * 1536 + 1024 + h * HD_ + tid;
    float acc = 0.f;
    for (int w = 0; w < SUB_; ++w) acc += sc[w] * vbase[(size_t)w * 1536];
    ctx[((size_t)(b * S_ + s)) * D_ + h * HD_ + tid] = acc * inv;
  }
}

// ---------------------------------------------------------------------------
extern "C" void kernel_launch(void* const* d_in, const int* in_sizes, int n_in,
                              void* d_out, int out_size, void* d_ws,
                              size_t ws_size, hipStream_t stream) {
  (void)in_sizes; (void)n_in; (void)out_size; (void)ws_size;
  const float* values   = (const float*)d_in[0];
  const float* W_kqv    = (const float*)d_in[1];
  const float* b_kqv    = (const float*)d_in[2];
  const float* ln_gamma = (const float*)d_in[3];
  const float* ln_beta  = (const float*)d_in[4];
  const float* W_kernel = (const float*)d_in[5];
  const float* b_kernel = (const float*)d_in[6];
  const float* W_proj   = (const float*)d_in[7];
  const float* b_proj   = (const float*)d_in[8];
  float* out = (float*)d_out;

  float* kqv = (float*)d_ws;                       // M_ x 1536
  float* ctx = kqv + (size_t)M_ * 1536;            // M_ x 512
  float* x   = ctx + (size_t)M_ * D_;              // M_ x 2048

  dim3 blk(256);

  // kqv = values @ W_kqv + b_kqv
  gemm_kernel<0><<<dim3(1536 / 64, M_ / 64), blk, 0, stream>>>(
      values, W_kqv, b_kqv, nullptr, kqv, M_, 1536, D_, D_, 1536, 1536, 0);

  // layernorm k and q in place
  ln_kernel<<<2 * M_, 128, 0, stream>>>(kqv, ln_gamma, ln_beta);

  // windowed attention -> ctx
  attn_kernel<<<B_ * H_ * S_, 128, 0, stream>>>(kqv, ctx);

  // x = relu(ctx @ W_kernel + b_kernel)
  gemm_kernel<1><<<dim3(KS_ / 64, M_ / 64), blk, 0, stream>>>(
      ctx, W_kernel, b_kernel, nullptr, x, M_, KS_, D_, D_, KS_, KS_, 0);

  // out = x @ W_proj + b_proj + v
  gemm_kernel<2><<<dim3(D_ / 64, M_ / 64), blk, 0, stream>>>(
      x, W_proj, b_proj, kqv + 1024, out, M_, D_, KS_, KS_, D_, D_, 1536);
}

// Round 2
// 477.178 us; speedup vs baseline: 1.7622x; 1.7622x over previous
//
#include <hip/hip_runtime.h>
#include <hip/hip_bf16.h>

// Problem constants
#define B_ 2
#define S_ 2048
#define H_ 8
#define HD_ 64
#define WIN_ 64
#define SUB_ 129      // 1 + 2*WIN
#define D_ 512        // H*HD
#define KS_ 2048
#define M_ 4096       // B*S
#define LN_EPS 1e-3f

// ---------------------------------------------------------------------------
// Tiled fp32 GEMM: C[M,N] = A[M,K] @ B[K,N] + bias[N]  (+ epilogue)
// EPI: 0 = bias only, 1 = bias+relu, 2 = bias + extra[row*eld+col]
// 64x64 tile, BK=16, 256 threads, 4x4 per-thread microtile.
// ---------------------------------------------------------------------------
template <int EPI>
__global__ __launch_bounds__(256) void gemm_kernel(
    const float* __restrict__ A, const float* __restrict__ Bm,
    const float* __restrict__ bias, const float* __restrict__ extra,
    float* __restrict__ C, int M, int N, int K, int lda, int ldb, int ldc,
    int eld) {
  __shared__ float As[16][68];  // stored transposed: As[k][m], pad to 68
  __shared__ float Bs[16][64];

  const int tid = threadIdx.x;
  const int tx = tid & 15;        // n-group
  const int ty = tid >> 4;        // m-group
  const int row0 = blockIdx.y << 6;
  const int col0 = blockIdx.x << 6;

  const int arow = tid >> 2;            // 0..63
  const int acol = (tid & 3) << 2;      // 0,4,8,12
  const int brow = tid >> 4;            // 0..15
  const int bcol = (tid & 15) << 2;     // 0..60

  const float* aptr = A + (size_t)(row0 + arow) * lda + acol;
  const float* bptr = Bm + (size_t)brow * ldb + col0 + bcol;

  float acc[4][4] = {};

  for (int k0 = 0; k0 < K; k0 += 16) {
    float4 av = *(const float4*)aptr;
    float4 bv = *(const float4*)bptr;
    aptr += 16;
    bptr += (size_t)16 * ldb;

    __syncthreads();  // previous iteration's reads done before overwrite
    As[acol + 0][arow] = av.x;
    As[acol + 1][arow] = av.y;
    As[acol + 2][arow] = av.z;
    As[acol + 3][arow] = av.w;
    *(float4*)&Bs[brow][bcol] = bv;
    __syncthreads();

#pragma unroll
    for (int kk = 0; kk < 16; ++kk) {
      float4 a = *(const float4*)&As[kk][ty << 2];
      float4 b = *(const float4*)&Bs[kk][tx << 2];
      acc[0][0] += a.x * b.x; acc[0][1] += a.x * b.y;
      acc[0][2] += a.x * b.z; acc[0][3] += a.x * b.w;
      acc[1][0] += a.y * b.x; acc[1][1] += a.y * b.y;
      acc[1][2] += a.y * b.z; acc[1][3] += a.y * b.w;
      acc[2][0] += a.z * b.x; acc[2][1] += a.z * b.y;
      acc[2][2] += a.z * b.z; acc[2][3] += a.z * b.w;
      acc[3][0] += a.w * b.x; acc[3][1] += a.w * b.y;
      acc[3][2] += a.w * b.z; acc[3][3] += a.w * b.w;
    }
  }

#pragma unroll
  for (int i = 0; i < 4; ++i) {
    const int row = row0 + (ty << 2) + i;
    const int colb = col0 + (tx << 2);
    float4 o;
    float* po = &o.x;
#pragma unroll
    for (int j = 0; j < 4; ++j) {
      float v = acc[i][j] + bias[colb + j];
      if (EPI == 1) v = fmaxf(v, 0.f);
      if (EPI == 2) v += extra[(size_t)row * eld + colb + j];
      po[j] = v;
    }
    *(float4*)&C[(size_t)row * ldc + colb] = o;
  }
}

// ---------------------------------------------------------------------------
// LayerNorm in-place on k (cols 0..511) and q (cols 512..1023) of kqv rows.
// ---------------------------------------------------------------------------
__global__ __launch_bounds__(128) void ln_kernel(float* __restrict__ kqv,
                                                 const float* __restrict__ gamma,
                                                 const float* __restrict__ beta) {
  const int row = blockIdx.x;
  const int bs = row >> 1;
  const int which = row & 1;  // 0 = k, 1 = q
  float* p = kqv + (size_t)bs * 1536 + (which ? 512 : 0);
  const int tid = threadIdx.x;
  const int c = tid << 2;

  float4 xv = *(float4*)&p[c];
  float s = xv.x + xv.y + xv.z + xv.w;
  float ss = xv.x * xv.x + xv.y * xv.y + xv.z * xv.z + xv.w * xv.w;

#pragma unroll
  for (int off = 32; off > 0; off >>= 1) {
    s += __shfl_down(s, off);
    ss += __shfl_down(ss, off);
  }
  __shared__ float red[4];
  if ((tid & 63) == 0) {
    red[(tid >> 6) * 2 + 0] = s;
    red[(tid >> 6) * 2 + 1] = ss;
  }
  __syncthreads();
  const float tot = red[0] + red[2];
  const float tots = red[1] + red[3];
  const float mean = tot * (1.f / 512.f);
  const float var = tots * (1.f / 512.f) - mean * mean;
  const float rstd = rsqrtf(var + LN_EPS);

  float4 g = *(const float4*)&gamma[c];
  float4 bb = *(const float4*)&beta[c];
  xv.x = (xv.x - mean) * rstd * g.x + bb.x;
  xv.y = (xv.y - mean) * rstd * g.y + bb.y;
  xv.z = (xv.z - mean) * rstd * g.z + bb.z;
  xv.w = (xv.w - mean) * rstd * g.w + bb.w;
  *(float4*)&p[c] = xv;
}

// ---------------------------------------------------------------------------
// Windowed attention, query-tiled. One block (256 threads) per
// (b, h, tile of 32 queries). Union of the 32 windows is <= 160 keys.
// Phase 1: stage K-union + Q-tile in LDS. Phase 2: scores (Q in regs).
// Phase 3: intra-wave softmax (8 threads per query). Phase 4: restage V
// into the K buffer. Phase 5: PV from LDS.
// LDS: Ks 160*68*4 + Qs 32*68*4 + sc 32*132*4 + qinv = ~67.6 KB -> 2 blk/CU.
// ---------------------------------------------------------------------------
__global__ __launch_bounds__(256) void attn_kernel(const float* __restrict__ kqv,
                                                   float* __restrict__ ctx) {
  __shared__ float Ks[160 * 68];   // K-union, later reused for V
  __shared__ float Qs[32 * 68];
  __shared__ float sc[32 * 132];
  __shared__ float qinv[32];

  const int bid = blockIdx.x;      // (b*H + h)*64 + tile
  const int tile = bid & 63;
  const int h = (bid >> 6) & 7;
  const int b = bid >> 9;
  const int t0 = tile << 5;        // first query of tile

  // window-union geometry
  int g0 = t0 - WIN_;  if (g0 < 0) g0 = 0;  if (g0 > S_ - SUB_) g0 = S_ - SUB_;
  int gm = t0 + 31 - WIN_; if (gm < 0) gm = 0; if (gm > S_ - SUB_) gm = S_ - SUB_;
  const int KU = gm + SUB_ - g0;   // <= 160

  const int tid = threadIdx.x;
  const size_t rowb = (size_t)(b * S_);

  // stage K union: rows g0..g0+KU-1, 64 floats each, stride 68 in LDS
  for (int i = tid * 4; i < KU * 64; i += 1024) {
    const int w = i >> 6, d = i & 63;
    float4 v = *(const float4*)&kqv[(rowb + g0 + w) * 1536 + h * 64 + d];
    *(float4*)&Ks[w * 68 + d] = v;
  }
  // stage Q tile
  for (int i = tid * 4; i < 32 * 64; i += 1024) {
    const int q = i >> 6, d = i & 63;
    float4 v = *(const float4*)&kqv[(rowb + t0 + q) * 1536 + 512 + h * 64 + d];
    *(float4*)&Qs[q * 68 + d] = v;
  }
  __syncthreads();

  const int q = tid >> 3;          // 0..31
  const int wg = tid & 7;          // 0..7
  int st = t0 + q - WIN_;
  if (st < 0) st = 0;
  if (st > S_ - SUB_) st = S_ - SUB_;
  const int off = st - g0;         // 0..31

  // hoist Q row into registers
  float4 qreg[16];
#pragma unroll
  for (int d4 = 0; d4 < 16; ++d4) qreg[d4] = *(const float4*)&Qs[q * 68 + d4 * 4];

  // scores: each thread does wi = wg, wg+8, ...
  float lmax = -1e30f;
  for (int wi = wg; wi < SUB_; wi += 8) {
    const float* krow = &Ks[(off + wi) * 68];
    float dot = 0.f;
#pragma unroll
    for (int d4 = 0; d4 < 16; ++d4) {
      float4 kk = *(const float4*)&krow[d4 * 4];
      dot += qreg[d4].x * kk.x + qreg[d4].y * kk.y +
             qreg[d4].z * kk.z + qreg[d4].w * kk.w;
    }
    dot *= 0.125f;
    sc[q * 132 + wi] = dot;
    lmax = fmaxf(lmax, dot);
  }
  // softmax across the 8 threads owning this query (same wave)
#pragma unroll
  for (int m = 1; m < 8; m <<= 1) lmax = fmaxf(lmax, __shfl_xor(lmax, m));
  float lsum = 0.f;
  for (int wi = wg; wi < SUB_; wi += 8) {
    const float e = __expf(sc[q * 132 + wi] - lmax);
    sc[q * 132 + wi] = e;
    lsum += e;
  }
#pragma unroll
  for (int m = 1; m < 8; m <<= 1) lsum += __shfl_xor(lsum, m);
  if (wg == 0) qinv[q] = 1.f / lsum;

  __syncthreads();  // everyone done reading Ks + sc/qinv visible

  // restage V into the Ks buffer
  for (int i = tid * 4; i < KU * 64; i += 1024) {
    const int w = i >> 6, d = i & 63;
    float4 v = *(const float4*)&kqv[(rowb + g0 + w) * 1536 + 1024 + h * 64 + d];
    *(float4*)&Ks[w * 68 + d] = v;
  }
  __syncthreads();

  // PV: thread = (q, dg); 8 d-values per thread
  const int dg = tid & 7;
  const float* prow = &sc[q * 132];
  float4 acc0 = {0.f, 0.f, 0.f, 0.f}, acc1 = {0.f, 0.f, 0.f, 0.f};
  for (int wi = 0; wi < SUB_; ++wi) {
    const float p = prow[wi];
    const float* vrow = &Ks[(off + wi) * 68 + dg * 8];
    float4 v0 = *(const float4*)&vrow[0];
    float4 v1 = *(const float4*)&vrow[4];
    acc0.x += p * v0.x; acc0.y += p * v0.y; acc0.z += p * v0.z; acc0.w += p * v0.w;
    acc1.x += p * v1.x; acc1.y += p * v1.y; acc1.z += p * v1.z; acc1.w += p * v1.w;
  }
  const float inv = qinv[q];
  float* o = &ctx[(rowb + t0 + q) * D_ + h * 64 + dg * 8];
  float4 o0 = {acc0.x * inv, acc0.y * inv, acc0.z * inv, acc0.w * inv};
  float4 o1 = {acc1.x * inv, acc1.y * inv, acc1.z * inv, acc1.w * inv};
  *(float4*)&o[0] = o0;
  *(float4*)&o[4] = o1;
}

// ---------------------------------------------------------------------------
extern "C" void kernel_launch(void* const* d_in, const int* in_sizes, int n_in,
                              void* d_out, int out_size, void* d_ws,
                              size_t ws_size, hipStream_t stream) {
  (void)in_sizes; (void)n_in; (void)out_size; (void)ws_size;
  const float* values   = (const float*)d_in[0];
  const float* W_kqv    = (const float*)d_in[1];
  const float* b_kqv    = (const float*)d_in[2];
  const float* ln_gamma = (const float*)d_in[3];
  const float* ln_beta  = (const float*)d_in[4];
  const float* W_kernel = (const float*)d_in[5];
  const float* b_kernel = (const float*)d_in[6];
  const float* W_proj   = (const float*)d_in[7];
  const float* b_proj   = (const float*)d_in[8];
  float* out = (float*)d_out;

  float* kqv = (float*)d_ws;                       // M_ x 1536
  float* ctx = kqv + (size_t)M_ * 1536;            // M_ x 512
  float* x   = ctx + (size_t)M_ * D_;              // M_ x 2048

  dim3 blk(256);

  // kqv = values @ W_kqv + b_kqv
  gemm_kernel<0><<<dim3(1536 / 64, M_ / 64), blk, 0, stream>>>(
      values, W_kqv, b_kqv, nullptr, kqv, M_, 1536, D_, D_, 1536, 1536, 0);

  // layernorm k and q in place
  ln_kernel<<<2 * M_, 128, 0, stream>>>(kqv, ln_gamma, ln_beta);

  // windowed attention -> ctx  (32 queries per block)
  attn_kernel<<<B_ * H_ * (S_ / 32), 256, 0, stream>>>(kqv, ctx);

  // x = relu(ctx @ W_kernel + b_kernel)
  gemm_kernel<1><<<dim3(KS_ / 64, M_ / 64), blk, 0, stream>>>(
      ctx, W_kernel, b_kernel, nullptr, x, M_, KS_, D_, D_, KS_, KS_, 0);

  // out = x @ W_proj + b_proj + v
  gemm_kernel<2><<<dim3(D_ / 64, M_ / 64), blk, 0, stream>>>(
      x, W_proj, b_proj, kqv + 1024, out, M_, D_, KS_, KS_, D_, D_, 1536);
}

// Round 3
// 220.670 us; speedup vs baseline: 3.8105x; 2.1624x over previous
//
#include <hip/hip_runtime.h>
#include <hip/hip_bf16.h>

// Problem constants
#define B_ 2
#define S_ 2048
#define H_ 8
#define HD_ 64
#define WIN_ 64
#define SUB_ 129      // 1 + 2*WIN
#define D_ 512        // H*HD
#define KS_ 2048
#define M_ 4096       // B*S
#define LN_EPS 1e-3f

typedef unsigned short u16;
typedef short bf16x8 __attribute__((ext_vector_type(8)));
typedef float f32x4 __attribute__((ext_vector_type(4)));

// RNE float->bf16 (finite inputs only)
__device__ inline u16 f2bf(float x) {
  unsigned int u = __float_as_uint(x);
  return (u16)((u + 0x7fffu + ((u >> 16) & 1u)) >> 16);
}

__device__ inline void gll16(const u16* g, u16* l) {
  __builtin_amdgcn_global_load_lds(
      (const __attribute__((address_space(1))) void*)g,
      (__attribute__((address_space(3))) void*)l, 16, 0, 0);
}

// ---------------------------------------------------------------------------
// bf16 MFMA GEMM: C[M,N] = A[M,K] @ Bt[N,K]^T + bias  (+ epilogue)
// A row-major M x K (bf16), Bt row-major N x K (bf16, pre-transposed weights).
// 128x128 tile, BK=32, 256 threads = 4 waves (2x2 of 64x64), 16x16x32 MFMA.
// LDS: As/Bs 128 rows x 32 bf16, 16-B chunks XOR-swizzled: phys chunk
// p = c ^ ((row>>1)&3)  -> ds_read_b128 fragment reads are <=2-way (free).
// Staged via global_load_lds width 16 (wave-uniform LDS base + lane*16).
// EPI: 0 = fp32 out + bias; 1 = bf16 out, relu(acc+bias); 2 = fp32 out +
// bias + extra[row*eld+col].
// ---------------------------------------------------------------------------
template <int EPI>
__global__ __launch_bounds__(256) void mfma_gemm(
    const u16* __restrict__ A, const u16* __restrict__ Bt,
    const float* __restrict__ bias, const float* __restrict__ extra,
    void* __restrict__ Cout, int K, int lda, int ldb, int ldc, int eld) {
  __shared__ __align__(16) u16 As[4096];  // 8 KB
  __shared__ __align__(16) u16 Bs[4096];

  const int tid = threadIdx.x;
  const int wv = tid >> 6;     // wave 0..3
  const int ln = tid & 63;
  const int row0 = blockIdx.y << 7;
  const int col0 = blockIdx.x << 7;

  // staging: wave wv handles instruction pair {2wv, 2wv+1} for A and B.
  // lane l: row = 16*inst + (l>>2), loads global chunk c = (l&3)^((l>>3)&3)
  // into phys chunk l&3  (so phys p holds data chunk p ^ ((row>>1)&3)).
  const int sr = ln >> 2;
  const int sc = ((ln & 3) ^ ((ln >> 3) & 3)) << 3;  // element offset in row
  const u16* ag0 = A + (size_t)(row0 + 32 * wv + sr) * lda + sc;
  const u16* ag1 = ag0 + (size_t)16 * lda;
  const u16* bg0 = Bt + (size_t)(col0 + 32 * wv + sr) * ldb + sc;
  const u16* bg1 = bg0 + (size_t)16 * ldb;
  u16* la0 = As + 1024 * wv;          // inst 2wv   (512 elems = 1 KB each)
  u16* la1 = la0 + 512;
  u16* lb0 = Bs + 1024 * wv;
  u16* lb1 = lb0 + 512;

  // fragment geometry
  const int q = ln >> 4;      // k-chunk quad
  const int r16 = ln & 15;
  const int wm = (wv & 1) << 6;
  const int wn = (wv >> 1) << 6;
  const int pA = ((((r16 >> 1) & 3) ^ q) << 4);  // swizzled chunk byte offset
  const char* Ab = (const char*)As;
  const char* Bb = (const char*)Bs;
  const int abase = (wm + r16) << 6;   // row*64 bytes
  const int bbase = (wn + r16) << 6;

  f32x4 acc[4][4];
#pragma unroll
  for (int i = 0; i < 4; ++i)
#pragma unroll
    for (int j = 0; j < 4; ++j) acc[i][j] = (f32x4){0.f, 0.f, 0.f, 0.f};

  for (int k0 = 0; k0 < K; k0 += 32) {
    __syncthreads();  // previous iter's ds_reads drained before overwrite
    gll16(ag0, la0);
    gll16(ag1, la1);
    gll16(bg0, lb0);
    gll16(bg1, lb1);
    ag0 += 32; ag1 += 32; bg0 += 32; bg1 += 32;
    __syncthreads();  // drains vmcnt(0): staged data visible to all waves

    bf16x8 af[4], bfr[4];
#pragma unroll
    for (int mi = 0; mi < 4; ++mi)
      af[mi] = *(const bf16x8*)(Ab + abase + mi * 1024 + pA);
#pragma unroll
    for (int ni = 0; ni < 4; ++ni)
      bfr[ni] = *(const bf16x8*)(Bb + bbase + ni * 1024 + pA);
#pragma unroll
    for (int mi = 0; mi < 4; ++mi)
#pragma unroll
      for (int ni = 0; ni < 4; ++ni)
        acc[mi][ni] = __builtin_amdgcn_mfma_f32_16x16x32_bf16(
            af[mi], bfr[ni], acc[mi][ni], 0, 0, 0);
  }

  // epilogue: C/D layout col = lane&15, row = quad*4 + reg
  const int colb = col0 + wn + r16;
  float bv[4];
#pragma unroll
  for (int ni = 0; ni < 4; ++ni) bv[ni] = bias[colb + ni * 16];

#pragma unroll
  for (int mi = 0; mi < 4; ++mi) {
#pragma unroll
    for (int ni = 0; ni < 4; ++ni) {
      const int col = colb + ni * 16;
#pragma unroll
      for (int r = 0; r < 4; ++r) {
        const int row = row0 + wm + mi * 16 + (q << 2) + r;
        float v = acc[mi][ni][r] + bv[ni];
        if (EPI == 0) {
          ((float*)Cout)[(size_t)row * ldc + col] = v;
        } else if (EPI == 1) {
          ((u16*)Cout)[(size_t)row * ldc + col] = f2bf(fmaxf(v, 0.f));
        } else {
          ((float*)Cout)[(size_t)row * ldc + col] =
              v + extra[(size_t)row * eld + col];
        }
      }
    }
  }
}

// ---------------------------------------------------------------------------
// fp32 -> bf16 elementwise (n multiple of 2048)
// ---------------------------------------------------------------------------
__global__ __launch_bounds__(256) void cvt_kernel(const float* __restrict__ in,
                                                  u16* __restrict__ out) {
  const int i = (blockIdx.x * 256 + threadIdx.x) * 8;
  float4 a = *(const float4*)&in[i];
  float4 b = *(const float4*)&in[i + 4];
  union { u16 u[8]; uint4 v; } pk;
  pk.u[0] = f2bf(a.x); pk.u[1] = f2bf(a.y); pk.u[2] = f2bf(a.z); pk.u[3] = f2bf(a.w);
  pk.u[4] = f2bf(b.x); pk.u[5] = f2bf(b.y); pk.u[6] = f2bf(b.z); pk.u[7] = f2bf(b.w);
  *(uint4*)&out[i] = pk.v;
}

// ---------------------------------------------------------------------------
// fp32 W[K,N] -> bf16 Wt[N,K] transpose-convert. 32x32 tiles, 256 threads.
// grid = (N/32, K/32)
// ---------------------------------------------------------------------------
__global__ __launch_bounds__(256) void cvtT_kernel(const float* __restrict__ W,
                                                   u16* __restrict__ Wt, int K,
                                                   int N) {
  __shared__ float t[32][33];
  const int n0 = blockIdx.x << 5;
  const int k0 = blockIdx.y << 5;
  const int r = threadIdx.x >> 3;
  const int c4 = (threadIdx.x & 7) << 2;
  float4 v = *(const float4*)&W[(size_t)(k0 + r) * N + n0 + c4];
  t[r][c4 + 0] = v.x; t[r][c4 + 1] = v.y; t[r][c4 + 2] = v.z; t[r][c4 + 3] = v.w;
  __syncthreads();
  ushort4 o;
  o.x = f2bf(t[c4 + 0][r]); o.y = f2bf(t[c4 + 1][r]);
  o.z = f2bf(t[c4 + 2][r]); o.w = f2bf(t[c4 + 3][r]);
  *(ushort4*)&Wt[(size_t)(n0 + r) * K + k0 + c4] = o;
}

// ---------------------------------------------------------------------------
// LayerNorm in-place on k (cols 0..511) and q (cols 512..1023) of kqv rows.
// ---------------------------------------------------------------------------
__global__ __launch_bounds__(128) void ln_kernel(float* __restrict__ kqv,
                                                 const float* __restrict__ gamma,
                                                 const float* __restrict__ beta) {
  const int row = blockIdx.x;
  const int bs = row >> 1;
  const int which = row & 1;  // 0 = k, 1 = q
  float* p = kqv + (size_t)bs * 1536 + (which ? 512 : 0);
  const int tid = threadIdx.x;
  const int c = tid << 2;

  float4 xv = *(float4*)&p[c];
  float s = xv.x + xv.y + xv.z + xv.w;
  float ss = xv.x * xv.x + xv.y * xv.y + xv.z * xv.z + xv.w * xv.w;

#pragma unroll
  for (int off = 32; off > 0; off >>= 1) {
    s += __shfl_down(s, off);
    ss += __shfl_down(ss, off);
  }
  __shared__ float red[4];
  if ((tid & 63) == 0) {
    red[(tid >> 6) * 2 + 0] = s;
    red[(tid >> 6) * 2 + 1] = ss;
  }
  __syncthreads();
  const float tot = red[0] + red[2];
  const float tots = red[1] + red[3];
  const float mean = tot * (1.f / 512.f);
  const float var = tots * (1.f / 512.f) - mean * mean;
  const float rstd = rsqrtf(var + LN_EPS);

  float4 g = *(const float4*)&gamma[c];
  float4 bb = *(const float4*)&beta[c];
  xv.x = (xv.x - mean) * rstd * g.x + bb.x;
  xv.y = (xv.y - mean) * rstd * g.y + bb.y;
  xv.z = (xv.z - mean) * rstd * g.z + bb.z;
  xv.w = (xv.w - mean) * rstd * g.w + bb.w;
  *(float4*)&p[c] = xv;
}

// ---------------------------------------------------------------------------
// Windowed attention, query-tiled (32 queries/block). ctx written as bf16.
// ---------------------------------------------------------------------------
__global__ __launch_bounds__(256) void attn_kernel(const float* __restrict__ kqv,
                                                   u16* __restrict__ ctx) {
  __shared__ float Ks[160 * 68];   // K-union, later reused for V
  __shared__ float Qs[32 * 68];
  __shared__ float sc[32 * 132];
  __shared__ float qinv[32];

  const int bid = blockIdx.x;      // (b*H + h)*64 + tile
  const int tile = bid & 63;
  const int h = (bid >> 6) & 7;
  const int b = bid >> 9;
  const int t0 = tile << 5;

  int g0 = t0 - WIN_;  if (g0 < 0) g0 = 0;  if (g0 > S_ - SUB_) g0 = S_ - SUB_;
  int gm = t0 + 31 - WIN_; if (gm < 0) gm = 0; if (gm > S_ - SUB_) gm = S_ - SUB_;
  const int KU = gm + SUB_ - g0;   // <= 160

  const int tid = threadIdx.x;
  const size_t rowb = (size_t)(b * S_);

  for (int i = tid * 4; i < KU * 64; i += 1024) {
    const int w = i >> 6, d = i & 63;
    float4 v = *(const float4*)&kqv[(rowb + g0 + w) * 1536 + h * 64 + d];
    *(float4*)&Ks[w * 68 + d] = v;
  }
  for (int i = tid * 4; i < 32 * 64; i += 1024) {
    const int qq = i >> 6, d = i & 63;
    float4 v = *(const float4*)&kqv[(rowb + t0 + qq) * 1536 + 512 + h * 64 + d];
    *(float4*)&Qs[qq * 68 + d] = v;
  }
  __syncthreads();

  const int q = tid >> 3;          // 0..31
  const int wg = tid & 7;          // 0..7
  int st = t0 + q - WIN_;
  if (st < 0) st = 0;
  if (st > S_ - SUB_) st = S_ - SUB_;
  const int off = st - g0;

  float4 qreg[16];
#pragma unroll
  for (int d4 = 0; d4 < 16; ++d4) qreg[d4] = *(const float4*)&Qs[q * 68 + d4 * 4];

  float lmax = -1e30f;
  for (int wi = wg; wi < SUB_; wi += 8) {
    const float* krow = &Ks[(off + wi) * 68];
    float dot = 0.f;
#pragma unroll
    for (int d4 = 0; d4 < 16; ++d4) {
      float4 kk = *(const float4*)&krow[d4 * 4];
      dot += qreg[d4].x * kk.x + qreg[d4].y * kk.y +
             qreg[d4].z * kk.z + qreg[d4].w * kk.w;
    }
    dot *= 0.125f;
    sc[q * 132 + wi] = dot;
    lmax = fmaxf(lmax, dot);
  }
#pragma unroll
  for (int m = 1; m < 8; m <<= 1) lmax = fmaxf(lmax, __shfl_xor(lmax, m));
  float lsum = 0.f;
  for (int wi = wg; wi < SUB_; wi += 8) {
    const float e = __expf(sc[q * 132 + wi] - lmax);
    sc[q * 132 + wi] = e;
    lsum += e;
  }
#pragma unroll
  for (int m = 1; m < 8; m <<= 1) lsum += __shfl_xor(lsum, m);
  if (wg == 0) qinv[q] = 1.f / lsum;

  __syncthreads();

  for (int i = tid * 4; i < KU * 64; i += 1024) {
    const int w = i >> 6, d = i & 63;
    float4 v = *(const float4*)&kqv[(rowb + g0 + w) * 1536 + 1024 + h * 64 + d];
    *(float4*)&Ks[w * 68 + d] = v;
  }
  __syncthreads();

  const int dg = tid & 7;
  const float* prow = &sc[q * 132];
  float4 acc0 = {0.f, 0.f, 0.f, 0.f}, acc1 = {0.f, 0.f, 0.f, 0.f};
  for (int wi = 0; wi < SUB_; ++wi) {
    const float p = prow[wi];
    const float* vrow = &Ks[(off + wi) * 68 + dg * 8];
    float4 v0 = *(const float4*)&vrow[0];
    float4 v1 = *(const float4*)&vrow[4];
    acc0.x += p * v0.x; acc0.y += p * v0.y; acc0.z += p * v0.z; acc0.w += p * v0.w;
    acc1.x += p * v1.x; acc1.y += p * v1.y; acc1.z += p * v1.z; acc1.w += p * v1.w;
  }
  const float inv = qinv[q];
  union { u16 u[8]; uint4 v; } pk;
  pk.u[0] = f2bf(acc0.x * inv); pk.u[1] = f2bf(acc0.y * inv);
  pk.u[2] = f2bf(acc0.z * inv); pk.u[3] = f2bf(acc0.w * inv);
  pk.u[4] = f2bf(acc1.x * inv); pk.u[5] = f2bf(acc1.y * inv);
  pk.u[6] = f2bf(acc1.z * inv); pk.u[7] = f2bf(acc1.w * inv);
  *(uint4*)&ctx[(rowb + t0 + q) * D_ + h * 64 + dg * 8] = pk.v;
}

// ---------------------------------------------------------------------------
extern "C" void kernel_launch(void* const* d_in, const int* in_sizes, int n_in,
                              void* d_out, int out_size, void* d_ws,
                              size_t ws_size, hipStream_t stream) {
  (void)in_sizes; (void)n_in; (void)out_size; (void)ws_size;
  const float* values   = (const float*)d_in[0];
  const float* W_kqv    = (const float*)d_in[1];
  const float* b_kqv    = (const float*)d_in[2];
  const float* ln_gamma = (const float*)d_in[3];
  const float* ln_beta  = (const float*)d_in[4];
  const float* W_kernel = (const float*)d_in[5];
  const float* b_kernel = (const float*)d_in[6];
  const float* W_proj   = (const float*)d_in[7];
  const float* b_proj   = (const float*)d_in[8];
  float* out = (float*)d_out;

  // workspace carve (all 16-B aligned)
  float* kqv     = (float*)d_ws;                       // M x 1536 fp32
  u16*   vals_bf = (u16*)(kqv + (size_t)M_ * 1536);    // M x 512
  u16*   ctx_bf  = vals_bf + (size_t)M_ * 512;         // M x 512
  u16*   x_bf    = ctx_bf + (size_t)M_ * 512;          // M x 2048
  u16*   wkqv_t  = x_bf + (size_t)M_ * 2048;           // 1536 x 512
  u16*   wker_t  = wkqv_t + (size_t)1536 * 512;        // 2048 x 512
  u16*   wproj_t = wker_t + (size_t)2048 * 512;        // 512 x 2048

  // converts
  cvt_kernel<<<(M_ * 512) / 2048, 256, 0, stream>>>(values, vals_bf);
  cvtT_kernel<<<dim3(1536 / 32, 512 / 32), 256, 0, stream>>>(W_kqv, wkqv_t, 512, 1536);
  cvtT_kernel<<<dim3(2048 / 32, 512 / 32), 256, 0, stream>>>(W_kernel, wker_t, 512, 2048);
  cvtT_kernel<<<dim3(512 / 32, 2048 / 32), 256, 0, stream>>>(W_proj, wproj_t, 2048, 512);

  // kqv = values @ W_kqv + b_kqv   (fp32 out)
  mfma_gemm<0><<<dim3(1536 / 128, M_ / 128), 256, 0, stream>>>(
      vals_bf, wkqv_t, b_kqv, nullptr, kqv, 512, 512, 512, 1536, 0);

  ln_kernel<<<2 * M_, 128, 0, stream>>>(kqv, ln_gamma, ln_beta);

  attn_kernel<<<B_ * H_ * (S_ / 32), 256, 0, stream>>>(kqv, ctx_bf);

  // x = relu(ctx @ W_kernel + b_kernel)  (bf16 out)
  mfma_gemm<1><<<dim3(KS_ / 128, M_ / 128), 256, 0, stream>>>(
      ctx_bf, wker_t, b_kernel, nullptr, x_bf, 512, 512, 512, KS_, 0);

  // out = x @ W_proj + b_proj + v  (fp32 out)
  mfma_gemm<2><<<dim3(D_ / 128, M_ / 128), 256, 0, stream>>>(
      x_bf, wproj_t, b_proj, kqv + 1024, out, KS_, KS_, KS_, D_, 1536);
}

// Round 4
// 199.067 us; speedup vs baseline: 4.2241x; 1.1085x over previous
//
#include <hip/hip_runtime.h>
#include <hip/hip_bf16.h>

// Problem constants
#define B_ 2
#define S_ 2048
#define H_ 8
#define HD_ 64
#define WIN_ 64
#define SUB_ 129      // 1 + 2*WIN
#define D_ 512        // H*HD
#define KS_ 2048
#define M_ 4096       // B*S
#define LN_EPS 1e-3f

typedef unsigned short u16;
typedef short bf16x8 __attribute__((ext_vector_type(8)));
typedef float f32x4 __attribute__((ext_vector_type(4)));

// RNE float->bf16 (finite inputs only)
__device__ inline u16 f2bf(float x) {
  unsigned int u = __float_as_uint(x);
  return (u16)((u + 0x7fffu + ((u >> 16) & 1u)) >> 16);
}
__device__ inline float bf2f_lo(unsigned int u) {  // low bf16 of packed pair
  return __uint_as_float(u << 16);
}
__device__ inline float bf2f_hi(unsigned int u) {
  return __uint_as_float(u & 0xffff0000u);
}

__device__ inline void gll16(const u16* g, u16* l) {
  __builtin_amdgcn_global_load_lds(
      (const __attribute__((address_space(1))) void*)g,
      (__attribute__((address_space(3))) void*)l, 16, 0, 0);
}

// ---------------------------------------------------------------------------
// bf16 MFMA GEMM: C[M,N] = A[M,K] @ Bt[N,K]^T + bias  (+ epilogue)
// 128x128 tile, BK=64, 256 threads = 4 waves (2x2 of 64x64), 16x16x32 MFMA.
// Double-buffered LDS (2 x 32 KB): loads for tile k+1 are issued right after
// the barrier, so the vmcnt(0) drain at the NEXT barrier comes a full compute
// phase later (latency hidden).
// LDS rows: 64 bf16 = 8 chunks of 16 B, chunk XOR-swizzled: phys = c ^ (row&7)
// -> fragment ds_read_b128 is <=2-way bank-aliased (free), staging pattern is
// the natural wave-uniform-base + lane*16 of global_load_lds.
// XCD swizzle: id&7 selects an M-band of 4 tiles (512 rows) so each XCD's L2
// holds its A-band + all of B.
// EPI: 0 = fp32 out + bias; 1 = bf16 out, relu; 2 = fp32 out + bias + extra.
// ---------------------------------------------------------------------------
template <int EPI>
__global__ __launch_bounds__(256) void mfma_gemm(
    const u16* __restrict__ A, const u16* __restrict__ Bt,
    const float* __restrict__ bias, const float* __restrict__ extra,
    void* __restrict__ Cout, int K, int lda, int ldb, int ldc, int eld,
    int TN) {
  __shared__ __align__(16) u16 As[2][8192];  // 16 KB each
  __shared__ __align__(16) u16 Bs[2][8192];

  const int tid = threadIdx.x;
  const int wv = tid >> 6;
  const int ln = tid & 63;

  // XCD-aware tile decode (8 groups, each owns 4 consecutive M-tiles)
  const int id = blockIdx.x;
  const int xcd = id & 7;
  const int sub = id >> 3;
  const int tn = sub % TN;
  const int msub = sub / TN;
  const int row0 = (xcd * 4 + msub) << 7;
  const int col0 = tn << 7;

  // staging geometry: per gll16, lane l covers row (l>>3), phys chunk (l&7)
  // of an 8-row group; logical chunk = (l&7) ^ (row&7).
  const int lrow = ln >> 3;                  // 0..7
  const int lchunk = (ln & 7) ^ lrow;        // logical k-chunk
  const u16* ag = A + (size_t)(row0 + 32 * wv + lrow) * lda + lchunk * 8;
  const u16* bg = Bt + (size_t)(col0 + 32 * wv + lrow) * ldb + lchunk * 8;
  const int lbase = 32 * wv * 64;            // elements

  // fragment geometry
  const int q = ln >> 4;        // k-quad
  const int r16 = ln & 15;
  const int r8 = r16 & 7;
  const int wm = (wv & 1) << 6;
  const int wn = (wv >> 1) << 6;

  f32x4 acc[4][4];
#pragma unroll
  for (int i = 0; i < 4; ++i)
#pragma unroll
    for (int j = 0; j < 4; ++j) acc[i][j] = (f32x4){0.f, 0.f, 0.f, 0.f};

#define STAGE(buf, koff)                                            \
  do {                                                              \
    const u16* a0 = ag + (koff);                                    \
    const u16* b0 = bg + (koff);                                    \
    u16* la = &As[buf][lbase];                                      \
    u16* lb = &Bs[buf][lbase];                                      \
    gll16(a0, la);                                                  \
    gll16(a0 + 8 * (size_t)lda, la + 512);                          \
    gll16(a0 + 16 * (size_t)lda, la + 1024);                        \
    gll16(a0 + 24 * (size_t)lda, la + 1536);                        \
    gll16(b0, lb);                                                  \
    gll16(b0 + 8 * (size_t)ldb, lb + 512);                          \
    gll16(b0 + 16 * (size_t)ldb, lb + 1024);                        \
    gll16(b0 + 24 * (size_t)ldb, lb + 1536);                        \
  } while (0)

  const int nk = K >> 6;
  STAGE(0, 0);

  for (int ki = 0; ki < nk; ++ki) {
    __syncthreads();  // drains vmcnt: buf[ki&1] staged; prev reads done
    if (ki + 1 < nk) STAGE((ki + 1) & 1, (ki + 1) << 6);

    const char* Ab = (const char*)As[ki & 1];
    const char* Bb = (const char*)Bs[ki & 1];
#pragma unroll
    for (int ks = 0; ks < 2; ++ks) {
      const int pc = ((q + 4 * ks) ^ r8) << 4;  // swizzled chunk byte offset
      bf16x8 af[4], bfv[4];
#pragma unroll
      for (int mi = 0; mi < 4; ++mi)
        af[mi] = *(const bf16x8*)(Ab + (wm + 16 * mi + r16) * 128 + pc);
#pragma unroll
      for (int ni = 0; ni < 4; ++ni)
        bfv[ni] = *(const bf16x8*)(Bb + (wn + 16 * ni + r16) * 128 + pc);
#pragma unroll
      for (int mi = 0; mi < 4; ++mi)
#pragma unroll
        for (int ni = 0; ni < 4; ++ni)
          acc[mi][ni] = __builtin_amdgcn_mfma_f32_16x16x32_bf16(
              af[mi], bfv[ni], acc[mi][ni], 0, 0, 0);
    }
  }
#undef STAGE

  // epilogue: C/D layout col = lane&15, row = quad*4 + reg
  const int colb = col0 + wn + r16;
  float bv[4];
#pragma unroll
  for (int ni = 0; ni < 4; ++ni) bv[ni] = bias[colb + ni * 16];

#pragma unroll
  for (int mi = 0; mi < 4; ++mi) {
#pragma unroll
    for (int ni = 0; ni < 4; ++ni) {
      const int col = colb + ni * 16;
#pragma unroll
      for (int r = 0; r < 4; ++r) {
        const int row = row0 + wm + mi * 16 + (q << 2) + r;
        float v = acc[mi][ni][r] + bv[ni];
        if (EPI == 0) {
          ((float*)Cout)[(size_t)row * ldc + col] = v;
        } else if (EPI == 1) {
          ((u16*)Cout)[(size_t)row * ldc + col] = f2bf(fmaxf(v, 0.f));
        } else {
          ((float*)Cout)[(size_t)row * ldc + col] =
              v + extra[(size_t)row * eld + col];
        }
      }
    }
  }
}

// ---------------------------------------------------------------------------
// fp32 -> bf16 elementwise (n multiple of 2048)
// ---------------------------------------------------------------------------
__global__ __launch_bounds__(256) void cvt_kernel(const float* __restrict__ in,
                                                  u16* __restrict__ out) {
  const int i = (blockIdx.x * 256 + threadIdx.x) * 8;
  float4 a = *(const float4*)&in[i];
  float4 b = *(const float4*)&in[i + 4];
  union { u16 u[8]; uint4 v; } pk;
  pk.u[0] = f2bf(a.x); pk.u[1] = f2bf(a.y); pk.u[2] = f2bf(a.z); pk.u[3] = f2bf(a.w);
  pk.u[4] = f2bf(b.x); pk.u[5] = f2bf(b.y); pk.u[6] = f2bf(b.z); pk.u[7] = f2bf(b.w);
  *(uint4*)&out[i] = pk.v;
}

// ---------------------------------------------------------------------------
// fp32 W[K,N] -> bf16 Wt[N,K] transpose-convert. 32x32 tiles, 256 threads.
// ---------------------------------------------------------------------------
__global__ __launch_bounds__(256) void cvtT_kernel(const float* __restrict__ W,
                                                   u16* __restrict__ Wt, int K,
                                                   int N) {
  __shared__ float t[32][33];
  const int n0 = blockIdx.x << 5;
  const int k0 = blockIdx.y << 5;
  const int r = threadIdx.x >> 3;
  const int c4 = (threadIdx.x & 7) << 2;
  float4 v = *(const float4*)&W[(size_t)(k0 + r) * N + n0 + c4];
  t[r][c4 + 0] = v.x; t[r][c4 + 1] = v.y; t[r][c4 + 2] = v.z; t[r][c4 + 3] = v.w;
  __syncthreads();
  ushort4 o;
  o.x = f2bf(t[c4 + 0][r]); o.y = f2bf(t[c4 + 1][r]);
  o.z = f2bf(t[c4 + 2][r]); o.w = f2bf(t[c4 + 3][r]);
  *(ushort4*)&Wt[(size_t)(n0 + r) * K + k0 + c4] = o;
}

// ---------------------------------------------------------------------------
// LayerNorm in-place on k (cols 0..511) and q (cols 512..1023) of kqv rows.
// ---------------------------------------------------------------------------
__global__ __launch_bounds__(128) void ln_kernel(float* __restrict__ kqv,
                                                 const float* __restrict__ gamma,
                                                 const float* __restrict__ beta) {
  const int row = blockIdx.x;
  const int bs = row >> 1;
  const int which = row & 1;
  float* p = kqv + (size_t)bs * 1536 + (which ? 512 : 0);
  const int tid = threadIdx.x;
  const int c = tid << 2;

  float4 xv = *(float4*)&p[c];
  float s = xv.x + xv.y + xv.z + xv.w;
  float ss = xv.x * xv.x + xv.y * xv.y + xv.z * xv.z + xv.w * xv.w;

#pragma unroll
  for (int off = 32; off > 0; off >>= 1) {
    s += __shfl_down(s, off);
    ss += __shfl_down(ss, off);
  }
  __shared__ float red[4];
  if ((tid & 63) == 0) {
    red[(tid >> 6) * 2 + 0] = s;
    red[(tid >> 6) * 2 + 1] = ss;
  }
  __syncthreads();
  const float tot = red[0] + red[2];
  const float tots = red[1] + red[3];
  const float mean = tot * (1.f / 512.f);
  const float var = tots * (1.f / 512.f) - mean * mean;
  const float rstd = rsqrtf(var + LN_EPS);

  float4 g = *(const float4*)&gamma[c];
  float4 bb = *(const float4*)&beta[c];
  xv.x = (xv.x - mean) * rstd * g.x + bb.x;
  xv.y = (xv.y - mean) * rstd * g.y + bb.y;
  xv.z = (xv.z - mean) * rstd * g.z + bb.z;
  xv.w = (xv.w - mean) * rstd * g.w + bb.w;
  *(float4*)&p[c] = xv;
}

// ---------------------------------------------------------------------------
// Windowed attention, query-tiled (32 queries/block, 256 threads).
// K and V staged TOGETHER upfront as bf16 (stride 72 = 9 16B-chunks, odd ->
// <=2-way bank alias), Q direct to registers, fp32 scores/softmax in LDS.
// Only 2 barriers total; softmax is intra-wave (8 threads per query).
// LDS: 2*160*72*2 + 32*132*4 = 62.9 KB -> 2 blocks/CU.
// ---------------------------------------------------------------------------
__global__ __launch_bounds__(256) void attn_kernel(const float* __restrict__ kqv,
                                                   u16* __restrict__ ctx) {
  __shared__ __align__(16) u16 Ks[160 * 72];
  __shared__ __align__(16) u16 Vs[160 * 72];
  __shared__ float sc[32 * 132];

  const int bid = blockIdx.x;      // (b*H + h)*64 + tile
  const int tile = bid & 63;
  const int h = (bid >> 6) & 7;
  const int b = bid >> 9;
  const int t0 = tile << 5;

  int g0 = t0 - WIN_;  if (g0 < 0) g0 = 0;  if (g0 > S_ - SUB_) g0 = S_ - SUB_;
  int gm = t0 + 31 - WIN_; if (gm < 0) gm = 0; if (gm > S_ - SUB_) gm = S_ - SUB_;
  const int KU = gm + SUB_ - g0;   // <= 160

  const int tid = threadIdx.x;
  const size_t rowb = (size_t)(b * S_);

  // stage K and V (fp32 global -> bf16 LDS), interleaved loads
  for (int i = tid * 4; i < KU * 64; i += 1024) {
    const int w = i >> 6, d = i & 63;
    const float* kp = &kqv[(rowb + g0 + w) * 1536 + h * 64 + d];
    float4 kv = *(const float4*)kp;
    float4 vv = *(const float4*)(kp + 1024);
    ushort4 ko, vo;
    ko.x = f2bf(kv.x); ko.y = f2bf(kv.y); ko.z = f2bf(kv.z); ko.w = f2bf(kv.w);
    vo.x = f2bf(vv.x); vo.y = f2bf(vv.y); vo.z = f2bf(vv.z); vo.w = f2bf(vv.w);
    *(ushort4*)&Ks[w * 72 + d] = ko;
    *(ushort4*)&Vs[w * 72 + d] = vo;
  }

  const int q = tid >> 3;          // 0..31
  const int wg = tid & 7;          // 0..7
  int st = t0 + q - WIN_;
  if (st < 0) st = 0;
  if (st > S_ - SUB_) st = S_ - SUB_;
  const int off = st - g0;

  // Q row into registers (fp32, direct from global; L1 serves the 8x reuse)
  float4 qreg[16];
  const float* qp = &kqv[(rowb + t0 + q) * 1536 + 512 + h * 64];
#pragma unroll
  for (int d4 = 0; d4 < 16; ++d4) qreg[d4] = *(const float4*)&qp[d4 * 4];

  __syncthreads();  // K/V staged

  // scores + online max
  float lmax = -1e30f;
  for (int wi = wg; wi < SUB_; wi += 8) {
    const u16* krow = &Ks[(off + wi) * 72];
    float dot = 0.f;
#pragma unroll
    for (int c = 0; c < 8; ++c) {
      uint4 kv = *(const uint4*)&krow[c * 8];
      float4 qa = qreg[c * 2], qb = qreg[c * 2 + 1];
      dot += qa.x * bf2f_lo(kv.x) + qa.y * bf2f_hi(kv.x) +
             qa.z * bf2f_lo(kv.y) + qa.w * bf2f_hi(kv.y) +
             qb.x * bf2f_lo(kv.z) + qb.y * bf2f_hi(kv.z) +
             qb.z * bf2f_lo(kv.w) + qb.w * bf2f_hi(kv.w);
    }
    dot *= 0.125f;
    sc[q * 132 + wi] = dot;
    lmax = fmaxf(lmax, dot);
  }
#pragma unroll
  for (int m = 1; m < 8; m <<= 1) lmax = fmaxf(lmax, __shfl_xor(lmax, m));
  float lsum = 0.f;
  for (int wi = wg; wi < SUB_; wi += 8) {
    const float e = __expf(sc[q * 132 + wi] - lmax);
    sc[q * 132 + wi] = e;
    lsum += e;
  }
#pragma unroll
  for (int m = 1; m < 8; m <<= 1) lsum += __shfl_xor(lsum, m);
  const float inv = 1.f / lsum;

  __syncthreads();  // sc visible (also orders within-wave ds ops)

  // PV: thread = (q, dg=wg); 8 d-values per thread
  const int dg = wg;
  const float* prow = &sc[q * 132];
  float a0 = 0.f, a1 = 0.f, a2 = 0.f, a3 = 0.f;
  float a4 = 0.f, a5 = 0.f, a6 = 0.f, a7 = 0.f;
  for (int wi = 0; wi < SUB_; ++wi) {
    const float p = prow[wi];
    const uint4 vv = *(const uint4*)&Vs[(off + wi) * 72 + dg * 8];
    a0 += p * bf2f_lo(vv.x); a1 += p * bf2f_hi(vv.x);
    a2 += p * bf2f_lo(vv.y); a3 += p * bf2f_hi(vv.y);
    a4 += p * bf2f_lo(vv.z); a5 += p * bf2f_hi(vv.z);
    a6 += p * bf2f_lo(vv.w); a7 += p * bf2f_hi(vv.w);
  }
  union { u16 u[8]; uint4 v; } pk;
  pk.u[0] = f2bf(a0 * inv); pk.u[1] = f2bf(a1 * inv);
  pk.u[2] = f2bf(a2 * inv); pk.u[3] = f2bf(a3 * inv);
  pk.u[4] = f2bf(a4 * inv); pk.u[5] = f2bf(a5 * inv);
  pk.u[6] = f2bf(a6 * inv); pk.u[7] = f2bf(a7 * inv);
  *(uint4*)&ctx[(rowb + t0 + q) * D_ + h * 64 + dg * 8] = pk.v;
}

// ---------------------------------------------------------------------------
extern "C" void kernel_launch(void* const* d_in, const int* in_sizes, int n_in,
                              void* d_out, int out_size, void* d_ws,
                              size_t ws_size, hipStream_t stream) {
  (void)in_sizes; (void)n_in; (void)out_size; (void)ws_size;
  const float* values   = (const float*)d_in[0];
  const float* W_kqv    = (const float*)d_in[1];
  const float* b_kqv    = (const float*)d_in[2];
  const float* ln_gamma = (const float*)d_in[3];
  const float* ln_beta  = (const float*)d_in[4];
  const float* W_kernel = (const float*)d_in[5];
  const float* b_kernel = (const float*)d_in[6];
  const float* W_proj   = (const float*)d_in[7];
  const float* b_proj   = (const float*)d_in[8];
  float* out = (float*)d_out;

  // workspace carve (all 16-B aligned)
  float* kqv     = (float*)d_ws;                       // M x 1536 fp32
  u16*   vals_bf = (u16*)(kqv + (size_t)M_ * 1536);    // M x 512
  u16*   ctx_bf  = vals_bf + (size_t)M_ * 512;         // M x 512
  u16*   x_bf    = ctx_bf + (size_t)M_ * 512;          // M x 2048
  u16*   wkqv_t  = x_bf + (size_t)M_ * 2048;           // 1536 x 512
  u16*   wker_t  = wkqv_t + (size_t)1536 * 512;        // 2048 x 512
  u16*   wproj_t = wker_t + (size_t)2048 * 512;        // 512 x 2048

  // converts
  cvt_kernel<<<(M_ * 512) / 2048, 256, 0, stream>>>(values, vals_bf);
  cvtT_kernel<<<dim3(1536 / 32, 512 / 32), 256, 0, stream>>>(W_kqv, wkqv_t, 512, 1536);
  cvtT_kernel<<<dim3(2048 / 32, 512 / 32), 256, 0, stream>>>(W_kernel, wker_t, 512, 2048);
  cvtT_kernel<<<dim3(512 / 32, 2048 / 32), 256, 0, stream>>>(W_proj, wproj_t, 2048, 512);

  // kqv = values @ W_kqv + b_kqv   (fp32 out)   grid = 12n x 32m
  mfma_gemm<0><<<384, 256, 0, stream>>>(
      vals_bf, wkqv_t, b_kqv, nullptr, kqv, 512, 512, 512, 1536, 0, 12);

  ln_kernel<<<2 * M_, 128, 0, stream>>>(kqv, ln_gamma, ln_beta);

  attn_kernel<<<B_ * H_ * (S_ / 32), 256, 0, stream>>>(kqv, ctx_bf);

  // x = relu(ctx @ W_kernel + b_kernel)  (bf16 out)  grid = 16n x 32m
  mfma_gemm<1><<<512, 256, 0, stream>>>(
      ctx_bf, wker_t, b_kernel, nullptr, x_bf, 512, 512, 512, KS_, 0, 16);

  // out = x @ W_proj + b_proj + v  (fp32 out)  grid = 4n x 32m
  mfma_gemm<2><<<128, 256, 0, stream>>>(
      x_bf, wproj_t, b_proj, kqv + 1024, out, 2048, 2048, 2048, D_, 1536, 4);
}

// Round 5
// 174.694 us; speedup vs baseline: 4.8134x; 1.1395x over previous
//
#include <hip/hip_runtime.h>
#include <hip/hip_bf16.h>

// Problem constants
#define B_ 2
#define S_ 2048
#define H_ 8
#define HD_ 64
#define WIN_ 64
#define SUB_ 129      // 1 + 2*WIN
#define D_ 512        // H*HD
#define KS_ 2048
#define M_ 4096       // B*S
#define LN_EPS 1e-3f

typedef unsigned short u16;
typedef short bf16x8 __attribute__((ext_vector_type(8)));
typedef _Float16 f16x8 __attribute__((ext_vector_type(8)));
typedef float f32x4 __attribute__((ext_vector_type(4)));

// RNE float->bf16 (finite inputs only)
__device__ inline u16 f2bf(float x) {
  unsigned int u = __float_as_uint(x);
  return (u16)((u + 0x7fffu + ((u >> 16) & 1u)) >> 16);
}

__device__ inline void gll16(const u16* g, u16* l) {
  __builtin_amdgcn_global_load_lds(
      (const __attribute__((address_space(1))) void*)g,
      (__attribute__((address_space(3))) void*)l, 16, 0, 0);
}

// ---------------------------------------------------------------------------
// bf16 MFMA GEMM (unchanged from round 4): C = A @ Bt^T + bias (+ epilogue)
// 128x128 tile, BK=64, double-buffered global_load_lds, XOR chunk swizzle,
// XCD-aware M-band decode.
// ---------------------------------------------------------------------------
template <int EPI>
__global__ __launch_bounds__(256) void mfma_gemm(
    const u16* __restrict__ A, const u16* __restrict__ Bt,
    const float* __restrict__ bias, const float* __restrict__ extra,
    void* __restrict__ Cout, int K, int lda, int ldb, int ldc, int eld,
    int TN) {
  __shared__ __align__(16) u16 As[2][8192];
  __shared__ __align__(16) u16 Bs[2][8192];

  const int tid = threadIdx.x;
  const int wv = tid >> 6;
  const int ln = tid & 63;

  const int id = blockIdx.x;
  const int xcd = id & 7;
  const int sub = id >> 3;
  const int tn = sub % TN;
  const int msub = sub / TN;
  const int row0 = (xcd * 4 + msub) << 7;
  const int col0 = tn << 7;

  const int lrow = ln >> 3;
  const int lchunk = (ln & 7) ^ lrow;
  const u16* ag = A + (size_t)(row0 + 32 * wv + lrow) * lda + lchunk * 8;
  const u16* bg = Bt + (size_t)(col0 + 32 * wv + lrow) * ldb + lchunk * 8;
  const int lbase = 32 * wv * 64;

  const int q = ln >> 4;
  const int r16 = ln & 15;
  const int r8 = r16 & 7;
  const int wm = (wv & 1) << 6;
  const int wn = (wv >> 1) << 6;

  f32x4 acc[4][4];
#pragma unroll
  for (int i = 0; i < 4; ++i)
#pragma unroll
    for (int j = 0; j < 4; ++j) acc[i][j] = (f32x4){0.f, 0.f, 0.f, 0.f};

#define STAGE(buf, koff)                                            \
  do {                                                              \
    const u16* a0 = ag + (koff);                                    \
    const u16* b0 = bg + (koff);                                    \
    u16* la = &As[buf][lbase];                                      \
    u16* lb = &Bs[buf][lbase];                                      \
    gll16(a0, la);                                                  \
    gll16(a0 + 8 * (size_t)lda, la + 512);                          \
    gll16(a0 + 16 * (size_t)lda, la + 1024);                        \
    gll16(a0 + 24 * (size_t)lda, la + 1536);                        \
    gll16(b0, lb);                                                  \
    gll16(b0 + 8 * (size_t)ldb, lb + 512);                          \
    gll16(b0 + 16 * (size_t)ldb, lb + 1024);                        \
    gll16(b0 + 24 * (size_t)ldb, lb + 1536);                        \
  } while (0)

  const int nk = K >> 6;
  STAGE(0, 0);

  for (int ki = 0; ki < nk; ++ki) {
    __syncthreads();
    if (ki + 1 < nk) STAGE((ki + 1) & 1, (ki + 1) << 6);

    const char* Ab = (const char*)As[ki & 1];
    const char* Bb = (const char*)Bs[ki & 1];
#pragma unroll
    for (int ks = 0; ks < 2; ++ks) {
      const int pc = ((q + 4 * ks) ^ r8) << 4;
      bf16x8 af[4], bfv[4];
#pragma unroll
      for (int mi = 0; mi < 4; ++mi)
        af[mi] = *(const bf16x8*)(Ab + (wm + 16 * mi + r16) * 128 + pc);
#pragma unroll
      for (int ni = 0; ni < 4; ++ni)
        bfv[ni] = *(const bf16x8*)(Bb + (wn + 16 * ni + r16) * 128 + pc);
#pragma unroll
      for (int mi = 0; mi < 4; ++mi)
#pragma unroll
        for (int ni = 0; ni < 4; ++ni)
          acc[mi][ni] = __builtin_amdgcn_mfma_f32_16x16x32_bf16(
              af[mi], bfv[ni], acc[mi][ni], 0, 0, 0);
    }
  }
#undef STAGE

  const int colb = col0 + wn + r16;
  float bv[4];
#pragma unroll
  for (int ni = 0; ni < 4; ++ni) bv[ni] = bias[colb + ni * 16];

#pragma unroll
  for (int mi = 0; mi < 4; ++mi) {
#pragma unroll
    for (int ni = 0; ni < 4; ++ni) {
      const int col = colb + ni * 16;
#pragma unroll
      for (int r = 0; r < 4; ++r) {
        const int row = row0 + wm + mi * 16 + (q << 2) + r;
        float v = acc[mi][ni][r] + bv[ni];
        if (EPI == 0) {
          ((float*)Cout)[(size_t)row * ldc + col] = v;
        } else if (EPI == 1) {
          ((u16*)Cout)[(size_t)row * ldc + col] = f2bf(fmaxf(v, 0.f));
        } else {
          ((float*)Cout)[(size_t)row * ldc + col] =
              v + extra[(size_t)row * eld + col];
        }
      }
    }
  }
}

// ---------------------------------------------------------------------------
// fp32 -> bf16 elementwise (n multiple of 2048)
// ---------------------------------------------------------------------------
__global__ __launch_bounds__(256) void cvt_kernel(const float* __restrict__ in,
                                                  u16* __restrict__ out) {
  const int i = (blockIdx.x * 256 + threadIdx.x) * 8;
  float4 a = *(const float4*)&in[i];
  float4 b = *(const float4*)&in[i + 4];
  union { u16 u[8]; uint4 v; } pk;
  pk.u[0] = f2bf(a.x); pk.u[1] = f2bf(a.y); pk.u[2] = f2bf(a.z); pk.u[3] = f2bf(a.w);
  pk.u[4] = f2bf(b.x); pk.u[5] = f2bf(b.y); pk.u[6] = f2bf(b.z); pk.u[7] = f2bf(b.w);
  *(uint4*)&out[i] = pk.v;
}

// ---------------------------------------------------------------------------
// fp32 W[K,N] -> bf16 Wt[N,K] transpose-convert. 32x32 tiles, 256 threads.
// ---------------------------------------------------------------------------
__global__ __launch_bounds__(256) void cvtT_kernel(const float* __restrict__ W,
                                                   u16* __restrict__ Wt, int K,
                                                   int N) {
  __shared__ float t[32][33];
  const int n0 = blockIdx.x << 5;
  const int k0 = blockIdx.y << 5;
  const int r = threadIdx.x >> 3;
  const int c4 = (threadIdx.x & 7) << 2;
  float4 v = *(const float4*)&W[(size_t)(k0 + r) * N + n0 + c4];
  t[r][c4 + 0] = v.x; t[r][c4 + 1] = v.y; t[r][c4 + 2] = v.z; t[r][c4 + 3] = v.w;
  __syncthreads();
  ushort4 o;
  o.x = f2bf(t[c4 + 0][r]); o.y = f2bf(t[c4 + 1][r]);
  o.z = f2bf(t[c4 + 2][r]); o.w = f2bf(t[c4 + 3][r]);
  *(ushort4*)&Wt[(size_t)(n0 + r) * K + k0 + c4] = o;
}

// ---------------------------------------------------------------------------
// LayerNorm in-place on k (cols 0..511) and q (cols 512..1023) of kqv rows.
// ---------------------------------------------------------------------------
__global__ __launch_bounds__(128) void ln_kernel(float* __restrict__ kqv,
                                                 const float* __restrict__ gamma,
                                                 const float* __restrict__ beta) {
  const int row = blockIdx.x;
  const int bs = row >> 1;
  const int which = row & 1;
  float* p = kqv + (size_t)bs * 1536 + (which ? 512 : 0);
  const int tid = threadIdx.x;
  const int c = tid << 2;

  float4 xv = *(float4*)&p[c];
  float s = xv.x + xv.y + xv.z + xv.w;
  float ss = xv.x * xv.x + xv.y * xv.y + xv.z * xv.z + xv.w * xv.w;

#pragma unroll
  for (int off = 32; off > 0; off >>= 1) {
    s += __shfl_down(s, off);
    ss += __shfl_down(ss, off);
  }
  __shared__ float red[4];
  if ((tid & 63) == 0) {
    red[(tid >> 6) * 2 + 0] = s;
    red[(tid >> 6) * 2 + 1] = ss;
  }
  __syncthreads();
  const float tot = red[0] + red[2];
  const float tots = red[1] + red[3];
  const float mean = tot * (1.f / 512.f);
  const float var = tots * (1.f / 512.f) - mean * mean;
  const float rstd = rsqrtf(var + LN_EPS);

  float4 g = *(const float4*)&gamma[c];
  float4 bb = *(const float4*)&beta[c];
  xv.x = (xv.x - mean) * rstd * g.x + bb.x;
  xv.y = (xv.y - mean) * rstd * g.y + bb.y;
  xv.z = (xv.z - mean) * rstd * g.z + bb.z;
  xv.w = (xv.w - mean) * rstd * g.w + bb.w;
  *(float4*)&p[c] = xv;
}

// ---------------------------------------------------------------------------
// MFMA windowed attention. One block (256 thr / 4 waves) = (b, h, 64 queries).
// Key union = 192 rows (staged unconditionally; out-of-window masked; tail
// blocks read past kqv into finite workspace data, fully masked).
// Per wave (16-query m-tile):
//   QK: 24x mfma 16x16x32 bf16, Q pre-scaled 1/8.  S in C-layout regs.
//   softmax: per-row window mask, 16-lane shfl_xor max/sum, exp in regs.
//   P -> LDS as f16 (unnormalized, <=1), PV: 24x mfma 16x16x32 f16 vs V^T.
//   O scaled by 1/rowsum in epilogue, written bf16 to ctx.
// LDS: Ks 192x64 bf16 (24.5K) + Vt 64x192 f16 (24.5K) + Ps[4][16x192] f16
// (24.5K, first 8K doubles as Qs) = 73.7 KB -> 2 blocks/CU.
// All tiles 16B-chunk XOR-swizzled: phys = (c&~7)|((c^row)&7) -> b128 reads
// conflict-free.
// ---------------------------------------------------------------------------
__global__ __launch_bounds__(256) void attn_kernel(const float* __restrict__ kqv,
                                                   u16* __restrict__ ctx) {
  __shared__ __align__(16) u16 Ks[192 * 64];      // bf16
  __shared__ __align__(16) u16 Vt[64 * 192];      // f16, [d][key]
  __shared__ __align__(16) u16 Ps[4 * 16 * 192];  // f16; [0..4095] doubles as Qs

  const int bid = blockIdx.x;      // (b*H + h)*32 + tile
  const int tile = bid & 31;
  const int h = (bid >> 5) & 7;
  const int b = bid >> 8;
  const int t0 = tile << 6;        // first query (64 per block)

  int g0 = t0 - WIN_;
  if (g0 < 0) g0 = 0;
  if (g0 > S_ - SUB_) g0 = S_ - SUB_;

  const int tid = threadIdx.x;
  const size_t rowb = (size_t)(b * S_);

  // ---- stage K (bf16, swizzled b128 writes, coalesced reads) ----
#pragma unroll
  for (int it = 0; it < 6; ++it) {
    const int item = tid + it * 256;        // 192 keys * 8 chunks
    const int key = item >> 3, c = item & 7;
    const int phys = c ^ (key & 7);
    const float* kp = &kqv[(rowb + g0 + key) * 1536 + h * 64 + c * 8];
    float4 a = *(const float4*)kp;
    float4 bb = *(const float4*)(kp + 4);
    union { u16 u[8]; uint4 v; } pk;
    pk.u[0] = f2bf(a.x); pk.u[1] = f2bf(a.y); pk.u[2] = f2bf(a.z); pk.u[3] = f2bf(a.w);
    pk.u[4] = f2bf(bb.x); pk.u[5] = f2bf(bb.y); pk.u[6] = f2bf(bb.z); pk.u[7] = f2bf(bb.w);
    *(uint4*)&Ks[key * 64 + phys * 8] = pk.v;
  }
  // ---- stage Q (bf16, pre-scaled by 1/8) into Ps[0..4095] ----
#pragma unroll
  for (int it = 0; it < 2; ++it) {
    const int item = tid + it * 256;        // 64 q * 8 chunks
    const int qq = item >> 3, c = item & 7;
    const int phys = c ^ (qq & 7);
    const float* qp = &kqv[(rowb + t0 + qq) * 1536 + 512 + h * 64 + c * 8];
    float4 a = *(const float4*)qp;
    float4 bb = *(const float4*)(qp + 4);
    union { u16 u[8]; uint4 v; } pk;
    pk.u[0] = f2bf(a.x * 0.125f); pk.u[1] = f2bf(a.y * 0.125f);
    pk.u[2] = f2bf(a.z * 0.125f); pk.u[3] = f2bf(a.w * 0.125f);
    pk.u[4] = f2bf(bb.x * 0.125f); pk.u[5] = f2bf(bb.y * 0.125f);
    pk.u[6] = f2bf(bb.z * 0.125f); pk.u[7] = f2bf(bb.w * 0.125f);
    *(uint4*)&Ps[qq * 64 + phys * 8] = pk.v;
  }
  // ---- stage V^T (f16, key-major items: LDS-write conflict-free,
  //      global reads uncoalesced but L2-served) ----
#pragma unroll
  for (int it = 0; it < 12; ++it) {
    const int item = tid + it * 256;        // 192 keys * 16 d-groups
    const int dg = item / 192;
    const int key = item - dg * 192;
    const float* vp = &kqv[(rowb + g0 + key) * 1536 + 1024 + h * 64 + dg * 4];
    float4 v = *(const float4*)vp;
#pragma unroll
    for (int j = 0; j < 4; ++j) {
      const int d = dg * 4 + j;
      const int c = key >> 3;
      const int phys = (c & 24) | ((c ^ d) & 7);
      const float f = (j == 0) ? v.x : (j == 1) ? v.y : (j == 2) ? v.z : v.w;
      *(_Float16*)&Vt[d * 192 + phys * 8 + (key & 7)] = (_Float16)f;
    }
  }
  __syncthreads();  // B1: staging complete

  const int wv = tid >> 6;
  const int ln = tid & 63;
  const int quad = ln >> 4;
  const int l15 = ln & 15;
  const int l7 = l15 & 7;
  const int qbase = wv << 4;       // wave's 16-query m-tile

  // Q A-fragments (2 k-steps)
  bf16x8 qf[2];
#pragma unroll
  for (int ks = 0; ks < 2; ++ks) {
    const int phys = (ks * 4 + quad) ^ l7;
    qf[ks] = *(const bf16x8*)&Ps[(qbase + l15) * 64 + phys * 8];
  }

  // QK: S[16 x 192] = Q @ K^T
  f32x4 sacc[12];
#pragma unroll
  for (int nt = 0; nt < 12; ++nt) sacc[nt] = (f32x4){0.f, 0.f, 0.f, 0.f};
#pragma unroll
  for (int ks = 0; ks < 2; ++ks) {
    const int phys = (ks * 4 + quad) ^ l7;
#pragma unroll
    for (int nt = 0; nt < 12; ++nt) {
      bf16x8 kf = *(const bf16x8*)&Ks[(nt * 16 + l15) * 64 + phys * 8];
      sacc[nt] = __builtin_amdgcn_mfma_f32_16x16x32_bf16(qf[ks], kf, sacc[nt], 0, 0, 0);
    }
  }

  // per-row window offsets (rows quad*4+reg)
  int off[4];
#pragma unroll
  for (int r = 0; r < 4; ++r) {
    const int qg = t0 + qbase + quad * 4 + r;
    int st = qg - WIN_;
    if (st < 0) st = 0;
    if (st > S_ - SUB_) st = S_ - SUB_;
    off[r] = st - g0;
  }

  // mask + row max
  float rmax[4] = {-1e30f, -1e30f, -1e30f, -1e30f};
#pragma unroll
  for (int nt = 0; nt < 12; ++nt) {
    const int n = nt * 16 + l15;
#pragma unroll
    for (int r = 0; r < 4; ++r) {
      const bool valid = (n >= off[r]) && (n < off[r] + SUB_);
      const float v = valid ? sacc[nt][r] : -1e30f;
      sacc[nt][r] = v;
      rmax[r] = fmaxf(rmax[r], v);
    }
  }
#pragma unroll
  for (int m = 1; m < 16; m <<= 1)
#pragma unroll
    for (int r = 0; r < 4; ++r) rmax[r] = fmaxf(rmax[r], __shfl_xor(rmax[r], m));

  // exp + row sum (P kept in sacc)
  float rsum[4] = {0.f, 0.f, 0.f, 0.f};
#pragma unroll
  for (int nt = 0; nt < 12; ++nt) {
#pragma unroll
    for (int r = 0; r < 4; ++r) {
      const float e = __expf(sacc[nt][r] - rmax[r]);
      sacc[nt][r] = e;
      rsum[r] += e;
    }
  }
#pragma unroll
  for (int m = 1; m < 16; m <<= 1)
#pragma unroll
    for (int r = 0; r < 4; ++r) rsum[r] += __shfl_xor(rsum[r], m);
  float inv[4];
#pragma unroll
  for (int r = 0; r < 4; ++r) inv[r] = 1.f / rsum[r];

  __syncthreads();  // B2: all QK reads done; Qs region now dead

  // write P (f16) to wave's Ps region, swizzled
  u16* psw = &Ps[wv * 16 * 192];
#pragma unroll
  for (int nt = 0; nt < 12; ++nt) {
    const int n = nt * 16 + l15;
    const int c = n >> 3;
#pragma unroll
    for (int r = 0; r < 4; ++r) {
      const int m = quad * 4 + r;
      const int phys = (c & 24) | ((c ^ m) & 7);
      *(_Float16*)&psw[m * 192 + phys * 8 + (n & 7)] = (_Float16)sacc[nt][r];
    }
  }
  __syncthreads();  // B3: Ps visible

  // PV: O[16 x 64] = P @ (V^T)^T
  f32x4 oacc[4];
#pragma unroll
  for (int nt = 0; nt < 4; ++nt) oacc[nt] = (f32x4){0.f, 0.f, 0.f, 0.f};
#pragma unroll
  for (int ks = 0; ks < 6; ++ks) {
    const int c = ks * 4 + quad;
    const int phys = (c & 24) | ((c ^ l7) & 7);
    f16x8 pf = *(const f16x8*)&psw[l15 * 192 + phys * 8];
#pragma unroll
    for (int nt = 0; nt < 4; ++nt) {
      f16x8 vf = *(const f16x8*)&Vt[(nt * 16 + l15) * 192 + phys * 8];
      oacc[nt] = __builtin_amdgcn_mfma_f32_16x16x32_f16(pf, vf, oacc[nt], 0, 0, 0);
    }
  }

  // epilogue: scale by 1/rowsum, write bf16 ctx
#pragma unroll
  for (int nt = 0; nt < 4; ++nt) {
#pragma unroll
    for (int r = 0; r < 4; ++r) {
      const int row = t0 + qbase + quad * 4 + r;
      const int col = h * 64 + nt * 16 + l15;
      ctx[(rowb + row) * D_ + col] = f2bf(oacc[nt][r] * inv[r]);
    }
  }
}

// ---------------------------------------------------------------------------
extern "C" void kernel_launch(void* const* d_in, const int* in_sizes, int n_in,
                              void* d_out, int out_size, void* d_ws,
                              size_t ws_size, hipStream_t stream) {
  (void)in_sizes; (void)n_in; (void)out_size; (void)ws_size;
  const float* values   = (const float*)d_in[0];
  const float* W_kqv    = (const float*)d_in[1];
  const float* b_kqv    = (const float*)d_in[2];
  const float* ln_gamma = (const float*)d_in[3];
  const float* ln_beta  = (const float*)d_in[4];
  const float* W_kernel = (const float*)d_in[5];
  const float* b_kernel = (const float*)d_in[6];
  const float* W_proj   = (const float*)d_in[7];
  const float* b_proj   = (const float*)d_in[8];
  float* out = (float*)d_out;

  // workspace carve (all 16-B aligned)
  float* kqv     = (float*)d_ws;                       // M x 1536 fp32
  u16*   vals_bf = (u16*)(kqv + (size_t)M_ * 1536);    // M x 512
  u16*   ctx_bf  = vals_bf + (size_t)M_ * 512;         // M x 512
  u16*   x_bf    = ctx_bf + (size_t)M_ * 512;          // M x 2048
  u16*   wkqv_t  = x_bf + (size_t)M_ * 2048;           // 1536 x 512
  u16*   wker_t  = wkqv_t + (size_t)1536 * 512;        // 2048 x 512
  u16*   wproj_t = wker_t + (size_t)2048 * 512;        // 512 x 2048

  // converts
  cvt_kernel<<<(M_ * 512) / 2048, 256, 0, stream>>>(values, vals_bf);
  cvtT_kernel<<<dim3(1536 / 32, 512 / 32), 256, 0, stream>>>(W_kqv, wkqv_t, 512, 1536);
  cvtT_kernel<<<dim3(2048 / 32, 512 / 32), 256, 0, stream>>>(W_kernel, wker_t, 512, 2048);
  cvtT_kernel<<<dim3(512 / 32, 2048 / 32), 256, 0, stream>>>(W_proj, wproj_t, 2048, 512);

  // kqv = values @ W_kqv + b_kqv   (fp32 out)
  mfma_gemm<0><<<384, 256, 0, stream>>>(
      vals_bf, wkqv_t, b_kqv, nullptr, kqv, 512, 512, 512, 1536, 0, 12);

  ln_kernel<<<2 * M_, 128, 0, stream>>>(kqv, ln_gamma, ln_beta);

  // MFMA windowed attention -> ctx (bf16), 64 queries/block
  attn_kernel<<<B_ * H_ * (S_ / 64), 256, 0, stream>>>(kqv, ctx_bf);

  // x = relu(ctx @ W_kernel + b_kernel)  (bf16 out)
  mfma_gemm<1><<<512, 256, 0, stream>>>(
      ctx_bf, wker_t, b_kernel, nullptr, x_bf, 512, 512, 512, KS_, 0, 16);

  // out = x @ W_proj + b_proj + v  (fp32 out)
  mfma_gemm<2><<<128, 256, 0, stream>>>(
      x_bf, wproj_t, b_proj, kqv + 1024, out, 2048, 2048, 2048, D_, 1536, 4);
}

// Round 6
// 159.081 us; speedup vs baseline: 5.2858x; 1.0982x over previous
//
#include <hip/hip_runtime.h>
#include <hip/hip_bf16.h>

// Problem constants
#define B_ 2
#define S_ 2048
#define H_ 8
#define HD_ 64
#define WIN_ 64
#define SUB_ 129      // 1 + 2*WIN
#define D_ 512        // H*HD
#define KS_ 2048
#define M_ 4096       // B*S
#define LN_EPS 1e-3f

typedef unsigned short u16;
typedef short bf16x8 __attribute__((ext_vector_type(8)));
typedef float f32x4 __attribute__((ext_vector_type(4)));

// RNE float->bf16 (finite inputs only)
__device__ inline u16 f2bf(float x) {
  unsigned int u = __float_as_uint(x);
  return (u16)((u + 0x7fffu + ((u >> 16) & 1u)) >> 16);
}
__device__ inline float bf2f(u16 u) {
  return __uint_as_float(((unsigned int)u) << 16);
}
__device__ inline float bf2f_lo(unsigned int u) { return __uint_as_float(u << 16); }
__device__ inline float bf2f_hi(unsigned int u) { return __uint_as_float(u & 0xffff0000u); }

__device__ inline void gll16(const u16* g, u16* l) {
  __builtin_amdgcn_global_load_lds(
      (const __attribute__((address_space(1))) void*)g,
      (__attribute__((address_space(3))) void*)l, 16, 0, 0);
}

// ---------------------------------------------------------------------------
// bf16 MFMA GEMM, 128x128 tile, BK=64, dbuf global_load_lds, XOR swizzle.
// EPI: 1 = bf16 out, relu(acc+bias); 3 = bf16 out, acc+bias.
// ---------------------------------------------------------------------------
template <int EPI>
__global__ __launch_bounds__(256) void mfma_gemm(
    const u16* __restrict__ A, const u16* __restrict__ Bt,
    const float* __restrict__ bias, u16* __restrict__ Cout, int K, int lda,
    int ldb, int ldc, int TN) {
  __shared__ __align__(16) u16 As[2][8192];
  __shared__ __align__(16) u16 Bs[2][8192];

  const int tid = threadIdx.x;
  const int wv = tid >> 6;
  const int ln = tid & 63;

  const int id = blockIdx.x;
  const int xcd = id & 7;
  const int sub = id >> 3;
  const int tn = sub % TN;
  const int msub = sub / TN;
  const int row0 = (xcd * 4 + msub) << 7;
  const int col0 = tn << 7;

  const int lrow = ln >> 3;
  const int lchunk = (ln & 7) ^ lrow;
  const u16* ag = A + (size_t)(row0 + 32 * wv + lrow) * lda + lchunk * 8;
  const u16* bg = Bt + (size_t)(col0 + 32 * wv + lrow) * ldb + lchunk * 8;
  const int lbase = 32 * wv * 64;

  const int q = ln >> 4;
  const int r16 = ln & 15;
  const int r8 = r16 & 7;
  const int wm = (wv & 1) << 6;
  const int wn = (wv >> 1) << 6;

  f32x4 acc[4][4];
#pragma unroll
  for (int i = 0; i < 4; ++i)
#pragma unroll
    for (int j = 0; j < 4; ++j) acc[i][j] = (f32x4){0.f, 0.f, 0.f, 0.f};

#define STAGE(buf, koff)                                            \
  do {                                                              \
    const u16* a0 = ag + (koff);                                    \
    const u16* b0 = bg + (koff);                                    \
    u16* la = &As[buf][lbase];                                      \
    u16* lb = &Bs[buf][lbase];                                      \
    gll16(a0, la);                                                  \
    gll16(a0 + 8 * (size_t)lda, la + 512);                          \
    gll16(a0 + 16 * (size_t)lda, la + 1024);                        \
    gll16(a0 + 24 * (size_t)lda, la + 1536);                        \
    gll16(b0, lb);                                                  \
    gll16(b0 + 8 * (size_t)ldb, lb + 512);                          \
    gll16(b0 + 16 * (size_t)ldb, lb + 1024);                        \
    gll16(b0 + 24 * (size_t)ldb, lb + 1536);                        \
  } while (0)

  const int nk = K >> 6;
  STAGE(0, 0);

  for (int ki = 0; ki < nk; ++ki) {
    __syncthreads();
    if (ki + 1 < nk) STAGE((ki + 1) & 1, (ki + 1) << 6);

    const char* Ab = (const char*)As[ki & 1];
    const char* Bb = (const char*)Bs[ki & 1];
#pragma unroll
    for (int ks = 0; ks < 2; ++ks) {
      const int pc = ((q + 4 * ks) ^ r8) << 4;
      bf16x8 af[4], bfv[4];
#pragma unroll
      for (int mi = 0; mi < 4; ++mi)
        af[mi] = *(const bf16x8*)(Ab + (wm + 16 * mi + r16) * 128 + pc);
#pragma unroll
      for (int ni = 0; ni < 4; ++ni)
        bfv[ni] = *(const bf16x8*)(Bb + (wn + 16 * ni + r16) * 128 + pc);
#pragma unroll
      for (int mi = 0; mi < 4; ++mi)
#pragma unroll
        for (int ni = 0; ni < 4; ++ni)
          acc[mi][ni] = __builtin_amdgcn_mfma_f32_16x16x32_bf16(
              af[mi], bfv[ni], acc[mi][ni], 0, 0, 0);
    }
  }
#undef STAGE

  const int colb = col0 + wn + r16;
  float bv[4];
#pragma unroll
  for (int ni = 0; ni < 4; ++ni) bv[ni] = bias[colb + ni * 16];

#pragma unroll
  for (int mi = 0; mi < 4; ++mi) {
#pragma unroll
    for (int ni = 0; ni < 4; ++ni) {
      const int col = colb + ni * 16;
#pragma unroll
      for (int r = 0; r < 4; ++r) {
        const int row = row0 + wm + mi * 16 + (q << 2) + r;
        float v = acc[mi][ni][r] + bv[ni];
        if (EPI == 1) v = fmaxf(v, 0.f);
        Cout[(size_t)row * ldc + col] = f2bf(v);
      }
    }
  }
}

// ---------------------------------------------------------------------------
// 64x128-tile bf16 MFMA GEMM for the final projection (doubles block count).
// 4 waves each own 64 rows x 32 cols (acc[4][2]). BK=64 dbuf, XOR swizzle.
// Epilogue: fp32 out = acc + bias[col] + bf2f(extra[row*eld+col]).
// Grid: 8 xcd * MB msub * TN tn; row0 = (xcd*MB+msub)*64.
// ---------------------------------------------------------------------------
__global__ __launch_bounds__(256) void mfma_gemm64(
    const u16* __restrict__ A, const u16* __restrict__ Bt,
    const float* __restrict__ bias, const u16* __restrict__ extra,
    float* __restrict__ Cout, int K, int lda, int ldb, int ldc, int eld,
    int TN, int MB) {
  __shared__ __align__(16) u16 As[2][4096];   // 64 x 64
  __shared__ __align__(16) u16 Bs[2][8192];   // 128 x 64

  const int tid = threadIdx.x;
  const int wv = tid >> 6;
  const int ln = tid & 63;

  const int id = blockIdx.x;
  const int xcd = id & 7;
  const int sub = id >> 3;
  const int tn = sub % TN;
  const int msub = sub / TN;
  const int row0 = (xcd * MB + msub) << 6;
  const int col0 = tn << 7;

  const int lrow = ln >> 3;
  const int lchunk = (ln & 7) ^ lrow;
  const u16* ag = A + (size_t)(row0 + 16 * wv + lrow) * lda + lchunk * 8;
  const u16* bg = Bt + (size_t)(col0 + 32 * wv + lrow) * ldb + lchunk * 8;

  const int q = ln >> 4;
  const int r16 = ln & 15;
  const int r8 = r16 & 7;
  const int wn = wv << 5;

  f32x4 acc[4][2];
#pragma unroll
  for (int i = 0; i < 4; ++i)
#pragma unroll
    for (int j = 0; j < 2; ++j) acc[i][j] = (f32x4){0.f, 0.f, 0.f, 0.f};

#define STAGE64(buf, koff)                                          \
  do {                                                              \
    const u16* a0 = ag + (koff);                                    \
    const u16* b0 = bg + (koff);                                    \
    u16* la = &As[buf][wv * 1024];                                  \
    u16* lb = &Bs[buf][wv * 2048];                                  \
    gll16(a0, la);                                                  \
    gll16(a0 + 8 * (size_t)lda, la + 512);                          \
    gll16(b0, lb);                                                  \
    gll16(b0 + 8 * (size_t)ldb, lb + 512);                          \
    gll16(b0 + 16 * (size_t)ldb, lb + 1024);                        \
    gll16(b0 + 24 * (size_t)ldb, lb + 1536);                        \
  } while (0)

  const int nk = K >> 6;
  STAGE64(0, 0);

  for (int ki = 0; ki < nk; ++ki) {
    __syncthreads();
    if (ki + 1 < nk) STAGE64((ki + 1) & 1, (ki + 1) << 6);

    const char* Ab = (const char*)As[ki & 1];
    const char* Bb = (const char*)Bs[ki & 1];
#pragma unroll
    for (int ks = 0; ks < 2; ++ks) {
      const int pc = ((q + 4 * ks) ^ r8) << 4;
      bf16x8 af[4], bfv[2];
#pragma unroll
      for (int mi = 0; mi < 4; ++mi)
        af[mi] = *(const bf16x8*)(Ab + (16 * mi + r16) * 128 + pc);
#pragma unroll
      for (int ni = 0; ni < 2; ++ni)
        bfv[ni] = *(const bf16x8*)(Bb + (wn + 16 * ni + r16) * 128 + pc);
#pragma unroll
      for (int mi = 0; mi < 4; ++mi)
#pragma unroll
        for (int ni = 0; ni < 2; ++ni)
          acc[mi][ni] = __builtin_amdgcn_mfma_f32_16x16x32_bf16(
              af[mi], bfv[ni], acc[mi][ni], 0, 0, 0);
    }
  }
#undef STAGE64

  const int colb = col0 + wn + r16;
  float bv[2];
#pragma unroll
  for (int ni = 0; ni < 2; ++ni) bv[ni] = bias[colb + ni * 16];

#pragma unroll
  for (int mi = 0; mi < 4; ++mi) {
#pragma unroll
    for (int ni = 0; ni < 2; ++ni) {
      const int col = colb + ni * 16;
#pragma unroll
      for (int r = 0; r < 4; ++r) {
        const int row = row0 + mi * 16 + (q << 2) + r;
        Cout[(size_t)row * ldc + col] =
            acc[mi][ni][r] + bv[ni] + bf2f(extra[(size_t)row * eld + col]);
      }
    }
  }
}

// ---------------------------------------------------------------------------
// fp32 -> bf16 elementwise (n multiple of 2048)
// ---------------------------------------------------------------------------
__global__ __launch_bounds__(256) void cvt_kernel(const float* __restrict__ in,
                                                  u16* __restrict__ out) {
  const int i = (blockIdx.x * 256 + threadIdx.x) * 8;
  float4 a = *(const float4*)&in[i];
  float4 b = *(const float4*)&in[i + 4];
  union { u16 u[8]; uint4 v; } pk;
  pk.u[0] = f2bf(a.x); pk.u[1] = f2bf(a.y); pk.u[2] = f2bf(a.z); pk.u[3] = f2bf(a.w);
  pk.u[4] = f2bf(b.x); pk.u[5] = f2bf(b.y); pk.u[6] = f2bf(b.z); pk.u[7] = f2bf(b.w);
  *(uint4*)&out[i] = pk.v;
}

// ---------------------------------------------------------------------------
// fp32 W[K,N] -> bf16 Wt[N,K] transpose-convert. 32x32 tiles, 256 threads.
// ---------------------------------------------------------------------------
__global__ __launch_bounds__(256) void cvtT_kernel(const float* __restrict__ W,
                                                   u16* __restrict__ Wt, int K,
                                                   int N) {
  __shared__ float t[32][33];
  const int n0 = blockIdx.x << 5;
  const int k0 = blockIdx.y << 5;
  const int r = threadIdx.x >> 3;
  const int c4 = (threadIdx.x & 7) << 2;
  float4 v = *(const float4*)&W[(size_t)(k0 + r) * N + n0 + c4];
  t[r][c4 + 0] = v.x; t[r][c4 + 1] = v.y; t[r][c4 + 2] = v.z; t[r][c4 + 3] = v.w;
  __syncthreads();
  ushort4 o;
  o.x = f2bf(t[c4 + 0][r]); o.y = f2bf(t[c4 + 1][r]);
  o.z = f2bf(t[c4 + 2][r]); o.w = f2bf(t[c4 + 3][r]);
  *(ushort4*)&Wt[(size_t)(n0 + r) * K + k0 + c4] = o;
}

// ---------------------------------------------------------------------------
// LayerNorm in-place on bf16 k (cols 0..511) and q (cols 512..1023) of kqv.
// grid = 2*M blocks, 128 threads, 4 elems/thread. fp32 math.
// ---------------------------------------------------------------------------
__global__ __launch_bounds__(128) void ln_kernel(u16* __restrict__ kqv,
                                                 const float* __restrict__ gamma,
                                                 const float* __restrict__ beta) {
  const int row = blockIdx.x;
  const int bs = row >> 1;
  const int which = row & 1;
  u16* p = kqv + (size_t)bs * 1536 + (which ? 512 : 0);
  const int tid = threadIdx.x;
  const int c = tid << 2;

  uint2 raw = *(uint2*)&p[c];
  float x0 = bf2f_lo(raw.x), x1 = bf2f_hi(raw.x);
  float x2 = bf2f_lo(raw.y), x3 = bf2f_hi(raw.y);
  float s = x0 + x1 + x2 + x3;
  float ss = x0 * x0 + x1 * x1 + x2 * x2 + x3 * x3;

#pragma unroll
  for (int off = 32; off > 0; off >>= 1) {
    s += __shfl_down(s, off);
    ss += __shfl_down(ss, off);
  }
  __shared__ float red[4];
  if ((tid & 63) == 0) {
    red[(tid >> 6) * 2 + 0] = s;
    red[(tid >> 6) * 2 + 1] = ss;
  }
  __syncthreads();
  const float tot = red[0] + red[2];
  const float tots = red[1] + red[3];
  const float mean = tot * (1.f / 512.f);
  const float var = tots * (1.f / 512.f) - mean * mean;
  const float rstd = rsqrtf(var + LN_EPS);

  float4 g = *(const float4*)&gamma[c];
  float4 bb = *(const float4*)&beta[c];
  union { u16 u[4]; uint2 v; } o;
  o.u[0] = f2bf((x0 - mean) * rstd * g.x + bb.x);
  o.u[1] = f2bf((x1 - mean) * rstd * g.y + bb.y);
  o.u[2] = f2bf((x2 - mean) * rstd * g.z + bb.z);
  o.u[3] = f2bf((x3 - mean) * rstd * g.w + bb.w);
  *(uint2*)&p[c] = o.v;
}

// ---------------------------------------------------------------------------
// MFMA windowed attention (all-bf16). One block = (b, h, 64 queries).
// kqv is bf16 -> staging is pure u16 copies. Q-scale 1/8 folded into the
// post-QK mask step. P kept bf16; PV uses bf16 MFMA vs V^T.
// LDS: Ks 192x64 + Vt 64x192 + Ps 4x16x192 (first 8K doubles as Qs) = 73.7 KB.
// ---------------------------------------------------------------------------
__global__ __launch_bounds__(256) void attn_kernel(const u16* __restrict__ kqv,
                                                   u16* __restrict__ ctx) {
  __shared__ __align__(16) u16 Ks[192 * 64];
  __shared__ __align__(16) u16 Vt[64 * 192];
  __shared__ __align__(16) u16 Ps[4 * 16 * 192];

  const int bid = blockIdx.x;      // (b*H + h)*32 + tile
  const int tile = bid & 31;
  const int h = (bid >> 5) & 7;
  const int b = bid >> 8;
  const int t0 = tile << 6;

  int g0 = t0 - WIN_;
  if (g0 < 0) g0 = 0;
  if (g0 > S_ - SUB_) g0 = S_ - SUB_;

  const int tid = threadIdx.x;
  const size_t rowb = (size_t)(b * S_);

  // ---- stage K (pure copy, swizzled b128 writes) ----
#pragma unroll
  for (int it = 0; it < 6; ++it) {
    const int item = tid + it * 256;        // 192 keys * 8 chunks
    const int key = item >> 3, c = item & 7;
    const int phys = c ^ (key & 7);
    uint4 v = *(const uint4*)&kqv[(rowb + g0 + key) * 1536 + h * 64 + c * 8];
    *(uint4*)&Ks[key * 64 + phys * 8] = v;
  }
  // ---- stage Q (pure copy) into Ps[0..4095] ----
#pragma unroll
  for (int it = 0; it < 2; ++it) {
    const int item = tid + it * 256;        // 64 q * 8 chunks
    const int qq = item >> 3, c = item & 7;
    const int phys = c ^ (qq & 7);
    uint4 v = *(const uint4*)&kqv[(rowb + t0 + qq) * 1536 + 512 + h * 64 + c * 8];
    *(uint4*)&Ps[qq * 64 + phys * 8] = v;
  }
  // ---- stage V^T (u16 scatter) ----
#pragma unroll
  for (int it = 0; it < 12; ++it) {
    const int item = tid + it * 256;        // 192 keys * 16 d-groups
    const int dg = item >> 7 == 0 ? item / 192 : item / 192;  // plain div
    const int key = item - dg * 192;
    uint2 v = *(const uint2*)&kqv[(rowb + g0 + key) * 1536 + 1024 + h * 64 + dg * 4];
    const int c = key >> 3;
    u16 e[4] = {(u16)(v.x & 0xffff), (u16)(v.x >> 16),
                (u16)(v.y & 0xffff), (u16)(v.y >> 16)};
#pragma unroll
    for (int j = 0; j < 4; ++j) {
      const int d = dg * 4 + j;
      const int phys = (c & 24) | ((c ^ d) & 7);
      Vt[d * 192 + phys * 8 + (key & 7)] = e[j];
    }
  }
  __syncthreads();  // B1: staging complete

  const int wv = tid >> 6;
  const int ln = tid & 63;
  const int quad = ln >> 4;
  const int l15 = ln & 15;
  const int l7 = l15 & 7;
  const int qbase = wv << 4;

  // Q A-fragments (2 k-steps)
  bf16x8 qf[2];
#pragma unroll
  for (int ks = 0; ks < 2; ++ks) {
    const int phys = (ks * 4 + quad) ^ l7;
    qf[ks] = *(const bf16x8*)&Ps[(qbase + l15) * 64 + phys * 8];
  }

  // QK: S[16 x 192] = Q @ K^T
  f32x4 sacc[12];
#pragma unroll
  for (int nt = 0; nt < 12; ++nt) sacc[nt] = (f32x4){0.f, 0.f, 0.f, 0.f};
#pragma unroll
  for (int ks = 0; ks < 2; ++ks) {
    const int phys = (ks * 4 + quad) ^ l7;
#pragma unroll
    for (int nt = 0; nt < 12; ++nt) {
      bf16x8 kf = *(const bf16x8*)&Ks[(nt * 16 + l15) * 64 + phys * 8];
      sacc[nt] = __builtin_amdgcn_mfma_f32_16x16x32_bf16(qf[ks], kf, sacc[nt], 0, 0, 0);
    }
  }

  // per-row window offsets
  int off[4];
#pragma unroll
  for (int r = 0; r < 4; ++r) {
    const int qg = t0 + qbase + quad * 4 + r;
    int st = qg - WIN_;
    if (st < 0) st = 0;
    if (st > S_ - SUB_) st = S_ - SUB_;
    off[r] = st - g0;
  }

  // mask + 1/8 scale + row max
  float rmax[4] = {-1e30f, -1e30f, -1e30f, -1e30f};
#pragma unroll
  for (int nt = 0; nt < 12; ++nt) {
    const int n = nt * 16 + l15;
#pragma unroll
    for (int r = 0; r < 4; ++r) {
      const bool valid = (n >= off[r]) && (n < off[r] + SUB_);
      const float v = valid ? sacc[nt][r] * 0.125f : -1e30f;
      sacc[nt][r] = v;
      rmax[r] = fmaxf(rmax[r], v);
    }
  }
#pragma unroll
  for (int m = 1; m < 16; m <<= 1)
#pragma unroll
    for (int r = 0; r < 4; ++r) rmax[r] = fmaxf(rmax[r], __shfl_xor(rmax[r], m));

  // exp + row sum
  float rsum[4] = {0.f, 0.f, 0.f, 0.f};
#pragma unroll
  for (int nt = 0; nt < 12; ++nt) {
#pragma unroll
    for (int r = 0; r < 4; ++r) {
      const float e = __expf(sacc[nt][r] - rmax[r]);
      sacc[nt][r] = e;
      rsum[r] += e;
    }
  }
#pragma unroll
  for (int m = 1; m < 16; m <<= 1)
#pragma unroll
    for (int r = 0; r < 4; ++r) rsum[r] += __shfl_xor(rsum[r], m);
  float inv[4];
#pragma unroll
  for (int r = 0; r < 4; ++r) inv[r] = 1.f / rsum[r];

  __syncthreads();  // B2: QK reads done; Qs region dead

  // write P (bf16, unnormalized) to wave's Ps region, swizzled
  u16* psw = &Ps[wv * 16 * 192];
#pragma unroll
  for (int nt = 0; nt < 12; ++nt) {
    const int n = nt * 16 + l15;
    const int c = n >> 3;
#pragma unroll
    for (int r = 0; r < 4; ++r) {
      const int m = quad * 4 + r;
      const int phys = (c & 24) | ((c ^ m) & 7);
      psw[m * 192 + phys * 8 + (n & 7)] = f2bf(sacc[nt][r]);
    }
  }
  __syncthreads();  // B3: Ps visible

  // PV: O[16 x 64] = P @ (V^T)^T
  f32x4 oacc[4];
#pragma unroll
  for (int nt = 0; nt < 4; ++nt) oacc[nt] = (f32x4){0.f, 0.f, 0.f, 0.f};
#pragma unroll
  for (int ks = 0; ks < 6; ++ks) {
    const int c = ks * 4 + quad;
    const int phys = (c & 24) | ((c ^ l7) & 7);
    bf16x8 pf = *(const bf16x8*)&psw[l15 * 192 + phys * 8];
#pragma unroll
    for (int nt = 0; nt < 4; ++nt) {
      bf16x8 vf = *(const bf16x8*)&Vt[(nt * 16 + l15) * 192 + phys * 8];
      oacc[nt] = __builtin_amdgcn_mfma_f32_16x16x32_bf16(pf, vf, oacc[nt], 0, 0, 0);
    }
  }

  // epilogue
#pragma unroll
  for (int nt = 0; nt < 4; ++nt) {
#pragma unroll
    for (int r = 0; r < 4; ++r) {
      const int row = t0 + qbase + quad * 4 + r;
      const int col = h * 64 + nt * 16 + l15;
      ctx[(rowb + row) * D_ + col] = f2bf(oacc[nt][r] * inv[r]);
    }
  }
}

// ---------------------------------------------------------------------------
extern "C" void kernel_launch(void* const* d_in, const int* in_sizes, int n_in,
                              void* d_out, int out_size, void* d_ws,
                              size_t ws_size, hipStream_t stream) {
  (void)in_sizes; (void)n_in; (void)out_size; (void)ws_size;
  const float* values   = (const float*)d_in[0];
  const float* W_kqv    = (const float*)d_in[1];
  const float* b_kqv    = (const float*)d_in[2];
  const float* ln_gamma = (const float*)d_in[3];
  const float* ln_beta  = (const float*)d_in[4];
  const float* W_kernel = (const float*)d_in[5];
  const float* b_kernel = (const float*)d_in[6];
  const float* W_proj   = (const float*)d_in[7];
  const float* b_proj   = (const float*)d_in[8];
  float* out = (float*)d_out;

  // workspace carve (all bf16 activations; 16-B aligned)
  u16* kqv     = (u16*)d_ws;                     // M x 1536
  u16* vals_bf = kqv + (size_t)M_ * 1536;        // M x 512
  u16* ctx_bf  = vals_bf + (size_t)M_ * 512;     // M x 512
  u16* x_bf    = ctx_bf + (size_t)M_ * 512;      // M x 2048
  u16* wkqv_t  = x_bf + (size_t)M_ * 2048;       // 1536 x 512
  u16* wker_t  = wkqv_t + (size_t)1536 * 512;    // 2048 x 512
  u16* wproj_t = wker_t + (size_t)2048 * 512;    // 512 x 2048

  // converts
  cvt_kernel<<<(M_ * 512) / 2048, 256, 0, stream>>>(values, vals_bf);
  cvtT_kernel<<<dim3(1536 / 32, 512 / 32), 256, 0, stream>>>(W_kqv, wkqv_t, 512, 1536);
  cvtT_kernel<<<dim3(2048 / 32, 512 / 32), 256, 0, stream>>>(W_kernel, wker_t, 512, 2048);
  cvtT_kernel<<<dim3(512 / 32, 2048 / 32), 256, 0, stream>>>(W_proj, wproj_t, 2048, 512);

  // kqv = values @ W_kqv + b_kqv   (bf16 out)
  mfma_gemm<3><<<384, 256, 0, stream>>>(
      vals_bf, wkqv_t, b_kqv, kqv, 512, 512, 512, 1536, 12);

  // layernorm k and q in place (bf16)
  ln_kernel<<<2 * M_, 128, 0, stream>>>(kqv, ln_gamma, ln_beta);

  // MFMA windowed attention -> ctx (bf16), 64 queries/block
  attn_kernel<<<B_ * H_ * (S_ / 64), 256, 0, stream>>>(kqv, ctx_bf);

  // x = relu(ctx @ W_kernel + b_kernel)  (bf16 out)
  mfma_gemm<1><<<512, 256, 0, stream>>>(
      ctx_bf, wker_t, b_kernel, x_bf, 512, 512, 512, KS_, 16);

  // out = x @ W_proj + b_proj + v  (fp32 out, 64x128 tiles, 256 blocks)
  mfma_gemm64<<<256, 256, 0, stream>>>(
      x_bf, wproj_t, b_proj, kqv + 1024, out, KS_, KS_, KS_, D_, 1536, 4, 8);
}